// Round 4
// baseline (386.484 us; speedup 1.0000x reference)
//
#include <hip/hip_runtime.h>
#include <hip/hip_bf16.h>
#include <cstddef>
#include <cstdint>

#define NTOK 8192      // N
#define CD   256       // C
#define HWPIX 16384    // H*W = 128*128
#define WIDTH 128
#define NSEQ 1024      // Ns

typedef __attribute__((ext_vector_type(8))) short bfrag;   // 8 bf16 = 4 VGPRs
typedef __attribute__((ext_vector_type(4))) float f32x4;

__device__ inline unsigned short f2bfu(float f) {
    __hip_bfloat16 h = __float2bfloat16(f);   // RTNE
    unsigned short u;
    __builtin_memcpy(&u, &h, 2);
    return u;
}
// RTNE to bf16 kept in HIGH 16 bits of returned u32 (f finite, not huge)
__device__ inline unsigned int rtn16(float f) {
    unsigned int u = __builtin_bit_cast(unsigned int, f);
    return u + 0x7fffu + ((u >> 16) & 1u);
}
__device__ inline float bits2f(unsigned int u) {
    return __builtin_bit_cast(float, u);
}

// ---------------------------------------------------------------------------
// 1. token2map scatter
// ---------------------------------------------------------------------------
__global__ __launch_bounds__(256) void scatter_k(const float* __restrict__ xsrc,
        const float* __restrict__ loc, float* __restrict__ feat,
        float* __restrict__ maskr) {
    int token = blockIdx.x;
    int b = token >> 13;
    int c = threadIdx.x;
    float lx = loc[token * 2 + 0];
    float ly = loc[token * 2 + 1];
    lx = fminf(fmaxf(lx, 0.f), 1.f) * 127.0f;
    ly = fminf(fmaxf(ly, 0.f), 1.f) * 127.0f;
    int ix = __float2int_rn(lx);
    int iy = __float2int_rn(ly);
    int p = b * HWPIX + iy * WIDTH + ix;
    atomicAdd(&feat[(size_t)p * CD + c], xsrc[(size_t)token * CD + c]);
    if (c == 0) atomicAdd(&maskr[p], 1.0f);
}

// ---------------------------------------------------------------------------
// 2. fused normalize + 3x3 gaussian reconstruct + 4x4 patch gather -> bf16 A
// ---------------------------------------------------------------------------
__global__ __launch_bounds__(256) void recon_fused(const float* __restrict__ feat,
        const float* __restrict__ maskr, unsigned short* __restrict__ apatch) {
    __shared__ float sw[9];
    __shared__ float sgb[9];
    __shared__ int   snp[9];
    __shared__ float sci;
    __shared__ float sbc;
    int p = blockIdx.x;
    int b = p >> 14;
    int pix = p & 16383;
    int y = pix >> 7, x = pix & 127;
    int c = threadIdx.x;
    const float e1 = 0.882496902584595f;
    const float e2 = 0.778800783071405f;
    const float snorm = 1.0f / (1.0f + 4.0f * e1 + 4.0f * e2);
    if (c < 9) {
        int dy = c / 3 - 1, dx = c % 3 - 1;
        int yy = y + dy, xx = x + dx;
        bool valid = (yy >= 0 && yy <= 127 && xx >= 0 && xx <= 127);
        int np_ = valid ? (b * HWPIX + yy * WIDTH + xx) : p;
        int manh = (dy != 0) + (dx != 0);
        float g = ((manh == 2) ? e2 : (manh == 1) ? e1 : 1.0f) * snorm;
        float m = maskr[np_];
        float bin = (m > 0.f) ? 1.f : 0.f;
        float inv = 1.0f / (m + 1e-6f);
        float vb = valid ? bin : 0.f;
        sw[c]  = g * vb * inv;
        sgb[c] = g * vb;
        snp[c] = np_;
        if (c == 4) { sci = bin * inv; sbc = bin; }
    }
    __syncthreads();
    float gm = ((sgb[0] + sgb[1]) + (sgb[2] + sgb[3])) +
               ((sgb[4] + sgb[5]) + (sgb[6] + sgb[7])) + sgb[8];
    float gf = 0.f;
    #pragma unroll
    for (int j = 0; j < 9; j++)
        gf += sw[j] * feat[(size_t)snp[j] * CD + c];
    float f_int = (gm > 0.f) ? (gf / (gm + 1e-6f)) : 0.f;
    float fc = feat[(size_t)p * CD + c] * sci;
    float res = fc + (1.f - sbc) * f_int;
    int r = b * 1024 + (y >> 2) * 32 + (x >> 2);
    int k16 = (y & 3) * 4 + (x & 3);
    apatch[(size_t)r * 4096 + k16 * 256 + c] = f2bfu(res);
}

// ---------------------------------------------------------------------------
// 3. prep_misc: all small prep work fused into one launch, switched on block
//    [0,4096)      wtrans  srw -> wTb
//    [4096,8192)   cvt x -> xbf
//    [8192,8256)   cvt Wq -> wqb ; [8256,8320) Wk ; [8320,8384) Wv
//    [8384,8640)   prep_wp Wp -> wpb [256][768] = [bh|bl|bh]
//    [8640,8648)   confE = exp(conf)
//    [8648,10696)  init xsb rows with srb (conv split-K accumulator)
// ---------------------------------------------------------------------------
__global__ __launch_bounds__(256) void prep_misc(
        const float* __restrict__ srw, const float* __restrict__ x,
        const float* __restrict__ Wq, const float* __restrict__ Wk,
        const float* __restrict__ Wv, const float* __restrict__ Wp,
        const float* __restrict__ conf, const float* __restrict__ srb,
        unsigned short* __restrict__ wTb, unsigned short* __restrict__ xbf,
        unsigned short* __restrict__ wqb, unsigned short* __restrict__ wkb,
        unsigned short* __restrict__ wvb, unsigned short* __restrict__ wpb,
        float* __restrict__ confE, float* __restrict__ xsb) {
    int gid = blockIdx.x, tid = threadIdx.x;
    if (gid < 4096) {                       // sr_w transpose
        int idx = gid * 256 + tid;
        int co = idx >> 12;
        int rest = idx & 4095;
        int k16 = rest >> 8;
        int ci = rest & 255;
        int kh = k16 >> 2, kw = k16 & 3;
        wTb[idx] = f2bfu(srw[(size_t)co * 4096 + ci * 16 + kh * 4 + kw]);
    } else if (gid < 8384) {                // fp32 -> bf16 converts
        const float* s; unsigned short* d; int base;
        if (gid < 8192)      { s = x;  d = xbf; base = gid - 4096; }
        else if (gid < 8256) { s = Wq; d = wqb; base = gid - 8192; }
        else if (gid < 8320) { s = Wk; d = wkb; base = gid - 8256; }
        else                 { s = Wv; d = wvb; base = gid - 8320; }
        int i = (base * 256 + tid) * 4;
        float4 v = *(const float4*)(s + i);
        ushort4 o;
        o.x = f2bfu(v.x); o.y = f2bfu(v.y); o.z = f2bfu(v.z); o.w = f2bfu(v.w);
        *(ushort4*)(d + i) = o;
    } else if (gid < 8640) {                // Wp split
        int n = gid - 8384, t = tid;
        float w = Wp[n * 256 + t];
        unsigned short hu = f2bfu(w);
        float hf = bits2f(((unsigned int)hu) << 16);
        unsigned short lu = f2bfu(w - hf);
        wpb[n * 768 + t]       = hu;
        wpb[n * 768 + 256 + t] = lu;
        wpb[n * 768 + 512 + t] = hu;
    } else if (gid < 8648) {                // E = exp(conf)
        int i = (gid - 8640) * 256 + tid;
        confE[i] = __expf(conf[i]);
    } else {                                // xsb init with bias
        int row = gid - 8648;
        xsb[(size_t)row * 256 + tid] = srb[tid];
    }
}

// ---------------------------------------------------------------------------
// 4. bf16 MFMA GEMM: 128x128 tile, 4 waves, BK=32.
//    mode 0: C fp32 = acc + bias[col]
//    mode 1: atomicAdd into C (split-K; C pre-initialized with bias)
//    mode 2: bf16 permuted write: dstb[((b*8+h)<<rshift | r)*32 + d]
//            = bf16(acc*mult),  b=row>>rshift, r=row&mask, h=col>>5, d=col&31
// ---------------------------------------------------------------------------
__global__ __launch_bounds__(256) void bgemm(const unsigned short* __restrict__ A,
        const unsigned short* __restrict__ B, const float* __restrict__ bias,
        float* __restrict__ C, unsigned short* __restrict__ dstb,
        int M, int N, int K, int kSplit, int mode, int rshift, float mult) {
    __shared__ __align__(16) unsigned short As[128 * 32];
    __shared__ __align__(16) unsigned short Bs[128 * 32];
    int tid = threadIdx.x;
    int wave = tid >> 6, lane = tid & 63, m15 = lane & 15, quad = lane >> 4;
    int wr = (wave >> 1) * 64, wc = (wave & 1) * 64;
    int m0 = blockIdx.y * 128, n0 = blockIdx.x * 128;
    int kchunk = K / kSplit, k0 = blockIdx.z * kchunk;
    int srow = tid >> 2, sko = (tid & 3) * 8;
    f32x4 acc[4][4];
    #pragma unroll
    for (int i = 0; i < 4; i++)
        #pragma unroll
        for (int j = 0; j < 4; j++) acc[i][j] = (f32x4){0.f, 0.f, 0.f, 0.f};
    const unsigned short* Ag = A + (size_t)(m0 + srow) * K + k0 + sko;
    const unsigned short* Bg = B + (size_t)(n0 + srow) * K + k0 + sko;
    for (int kk = 0; kk < kchunk; kk += 32) {
        bfrag a0 = *(const bfrag*)(Ag + kk);
        bfrag a1 = *(const bfrag*)(Ag + (size_t)64 * K + kk);
        bfrag b0 = *(const bfrag*)(Bg + kk);
        bfrag b1 = *(const bfrag*)(Bg + (size_t)64 * K + kk);
        __syncthreads();
        *(bfrag*)&As[srow * 32 + sko] = a0;
        *(bfrag*)&As[(srow + 64) * 32 + sko] = a1;
        *(bfrag*)&Bs[srow * 32 + sko] = b0;
        *(bfrag*)&Bs[(srow + 64) * 32 + sko] = b1;
        __syncthreads();
        bfrag af[4], bfr[4];
        #pragma unroll
        for (int mi = 0; mi < 4; mi++)
            af[mi] = *(const bfrag*)&As[(wr + mi * 16 + m15) * 32 + quad * 8];
        #pragma unroll
        for (int ni = 0; ni < 4; ni++)
            bfr[ni] = *(const bfrag*)&Bs[(wc + ni * 16 + m15) * 32 + quad * 8];
        #pragma unroll
        for (int mi = 0; mi < 4; mi++)
            #pragma unroll
            for (int ni = 0; ni < 4; ni++)
                acc[mi][ni] = __builtin_amdgcn_mfma_f32_16x16x32_bf16(
                                  af[mi], bfr[ni], acc[mi][ni], 0, 0, 0);
    }
    if (mode == 2) {
        int rmask = (1 << rshift) - 1;
        #pragma unroll
        for (int mi = 0; mi < 4; mi++) {
            #pragma unroll
            for (int i = 0; i < 4; i++) {
                int row = m0 + wr + mi * 16 + quad * 4 + i;
                int b = row >> rshift, r = row & rmask;
                #pragma unroll
                for (int ni = 0; ni < 4; ni++) {
                    int col = n0 + wc + ni * 16 + m15;
                    int h = col >> 5, d = col & 31;
                    size_t di = ((((size_t)(b * 8 + h)) << rshift) + r) * 32 + d;
                    dstb[di] = f2bfu(acc[mi][ni][i] * mult);
                }
            }
        }
    } else {
        #pragma unroll
        for (int mi = 0; mi < 4; mi++) {
            #pragma unroll
            for (int i = 0; i < 4; i++) {
                size_t row = (size_t)(m0 + wr + mi * 16 + quad * 4 + i) * N;
                #pragma unroll
                for (int ni = 0; ni < 4; ni++) {
                    int col = n0 + wc + ni * 16 + m15;
                    float v = acc[mi][ni][i];
                    if (mode == 1) atomicAdd(&C[row + col], v);
                    else C[row + col] = v + (bias ? bias[col] : 0.f);
                }
            }
        }
    }
}

// ---------------------------------------------------------------------------
// 5. LayerNorm (C=256), fp32 in -> bf16 out
// ---------------------------------------------------------------------------
__global__ __launch_bounds__(256) void ln_k(const float* __restrict__ xs,
        const float* __restrict__ w, const float* __restrict__ bvec,
        unsigned short* __restrict__ outb) {
    int row = blockIdx.x;
    int c = threadIdx.x;
    float v = xs[(size_t)row * 256 + c];
    __shared__ float red[4];
    float s = v;
    #pragma unroll
    for (int o = 32; o >= 1; o >>= 1) s += __shfl_down(s, o, 64);
    if ((c & 63) == 0) red[c >> 6] = s;
    __syncthreads();
    float mean = (red[0] + red[1] + red[2] + red[3]) * (1.f / 256.f);
    __syncthreads();
    float d = v - mean;
    float s2 = d * d;
    #pragma unroll
    for (int o = 32; o >= 1; o >>= 1) s2 += __shfl_down(s2, o, 64);
    if ((c & 63) == 0) red[c >> 6] = s2;
    __syncthreads();
    float var = (red[0] + red[1] + red[2] + red[3]) * (1.f / 256.f);
    float r = 1.0f / sqrtf(var + 1e-5f);
    outb[(size_t)row * 256 + c] = f2bfu(d * r * w[c] + bvec[c]);
}

// ---------------------------------------------------------------------------
// 6. V' build: Vt[bh][48][1024] key-permuted bf16.
//    rows 0..31: E[j]*v[j][d]; row 32: E[j]; rows 33..47: 0.
//    Permutation: within each 64-key block, col 4*m+sub holds key m+sub*16.
// ---------------------------------------------------------------------------
__global__ __launch_bounds__(256) void prep_vt(const float* __restrict__ vbuf,
        const float* __restrict__ confE, unsigned short* __restrict__ vt) {
    int dr = blockIdx.x;               // 0..47 (V'-row)
    int bh = blockIdx.y;               // 0..15
    int b = bh >> 3, h = bh & 7;
    int t = threadIdx.x;
    int blk = t >> 4, m = t & 15;
    ushort4 o;
    if (dr < 33) {
        float vals[4];
        #pragma unroll
        for (int sub = 0; sub < 4; sub++) {
            int key = blk * 64 + m + sub * 16;
            float e = confE[b * NSEQ + key];
            vals[sub] = (dr == 32) ? e
                : e * vbuf[((size_t)(b * NSEQ + key)) * 256 + h * 32 + dr];
        }
        o.x = f2bfu(vals[0]); o.y = f2bfu(vals[1]);
        o.z = f2bfu(vals[2]); o.w = f2bfu(vals[3]);
    } else {
        o.x = o.y = o.z = o.w = 0;
    }
    *(ushort4*)&vt[((size_t)bh * 48 + dr) * NSEQ + blk * 64 + 4 * m] = o;
}

// ---------------------------------------------------------------------------
// 7. MFMA flash attention v4: 16 q-rows per wave (8192 waves -> 8 blocks/CU),
//    conf folded into V'/E (l computed by the 3rd PV MFMA), Q pre-scaled by
//    scale*log2e, P packed with v_cvt_pk. No barriers, no running max
//    (logits bounded: |qk*scale*log2e| < ~3).
// ---------------------------------------------------------------------------
__global__ __launch_bounds__(256, 6) void attn_v4(
        const unsigned short* __restrict__ Qb,   // [bh][8192][32] *scale*log2e
        const unsigned short* __restrict__ Kb,   // [bh][1024][32]
        const unsigned short* __restrict__ Vt,   // [bh][48][1024] permuted
        unsigned short* __restrict__ aout) {     // [16384][768] hi|hi|lo
    __shared__ __align__(16) unsigned short Pl[4 * 1152];  // 4 waves * 16*72
    int tid  = threadIdx.x;
    int wave = tid >> 6;
    int lane = tid & 63;
    int m15  = lane & 15;
    int quad = lane >> 4;
    int bh = blockIdx.y;
    int b  = bh >> 3;
    int h  = bh & 7;
    int qbase = blockIdx.x * 64 + wave * 16;

    const unsigned short* qp = Qb + ((size_t)bh * NTOK + qbase) * 32;
    bfrag Qa = *(const bfrag*)(qp + m15 * 32 + quad * 8);
    const unsigned short* kp = Kb + (size_t)bh * NSEQ * 32 + m15 * 32 + quad * 8;
    const unsigned short* vp = Vt + (size_t)bh * 48 * NSEQ + quad * 8;
    unsigned short* Pw = Pl + wave * 1152;

    f32x4 O[3];
    O[0] = O[1] = O[2] = (f32x4){0.f, 0.f, 0.f, 0.f};
    f32x4 zero = (f32x4){0.f, 0.f, 0.f, 0.f};

    for (int t0 = 0; t0 < NSEQ; t0 += 64) {
        // ---- S = Q K^T (4 MFMAs) ----
        f32x4 S[4];
        #pragma unroll
        for (int sub = 0; sub < 4; sub++) {
            bfrag kf = *(const bfrag*)(kp + t0 * 32 + sub * 512);
            S[sub] = __builtin_amdgcn_mfma_f32_16x16x32_bf16(Qa, kf, zero, 0, 0, 0);
        }
        // ---- P = exp2(S); pack pairs with v_cvt_pk into permuted cols ----
        #pragma unroll
        for (int r = 0; r < 4; r++) {
            float2 p01, p23;
            p01.x = exp2f(S[0][r]); p01.y = exp2f(S[1][r]);
            p23.x = exp2f(S[2][r]); p23.y = exp2f(S[3][r]);
            __hip_bfloat162 q01 = __float22bfloat162_rn(p01);
            __hip_bfloat162 q23 = __float22bfloat162_rn(p23);
            uint2 dd;
            __builtin_memcpy(&dd.x, &q01, 4);
            __builtin_memcpy(&dd.y, &q23, 4);
            *(uint2*)&Pw[(quad * 4 + r) * 72 + 4 * m15] = dd;
        }
        // ---- O += P V' (6 MFMAs; dt=2 accumulates l via E-row) ----
        #pragma unroll
        for (int kf2 = 0; kf2 < 2; kf2++) {
            bfrag Pa = *(const bfrag*)&Pw[m15 * 72 + kf2 * 32 + quad * 8];
            #pragma unroll
            for (int dt = 0; dt < 3; dt++) {
                bfrag vf = *(const bfrag*)(vp +
                    (size_t)(dt * 16 + m15) * NSEQ + t0 + kf2 * 32);
                O[dt] = __builtin_amdgcn_mfma_f32_16x16x32_bf16(Pa, vf, O[dt], 0, 0, 0);
            }
        }
    }
    // ---- epilogue: l lives in lane quad*16 of O[2]; broadcast, divide,
    //      write split hi/hi/lo bf16 rows of aout [16384][768] ----
    #pragma unroll
    for (int r = 0; r < 4; r++) {
        float lr = __shfl(O[2][r], (lane & 48), 64);
        float inv = 1.0f / lr;
        int row = b * NTOK + qbase + quad * 4 + r;
        size_t rb = (size_t)row * 768;
        #pragma unroll
        for (int dt = 0; dt < 2; dt++) {
            float o = O[dt][r] * inv;
            unsigned int hr = rtn16(o);
            unsigned short hu = hr >> 16;
            float hf = bits2f(hr & 0xffff0000u);
            unsigned short lu = rtn16(o - hf) >> 16;
            int col = h * 32 + dt * 16 + m15;
            aout[rb + col]       = hu;
            aout[rb + 256 + col] = hu;
            aout[rb + 512 + col] = lu;
        }
    }
}

// ---------------------------------------------------------------------------
extern "C" void kernel_launch(void* const* d_in, const int* in_sizes, int n_in,
                              void* d_out, int out_size, void* d_ws, size_t ws_size,
                              hipStream_t stream) {
    const float* x        = (const float*)d_in[0];
    const float* x_source = (const float*)d_in[1];
    const float* loc      = (const float*)d_in[2];
    const float* conf     = (const float*)d_in[3];
    const float* Wq       = (const float*)d_in[4];
    const float* Wk       = (const float*)d_in[5];
    const float* Wv       = (const float*)d_in[6];
    const float* srw      = (const float*)d_in[7];
    const float* srb      = (const float*)d_in[8];
    const float* lnw      = (const float*)d_in[9];
    const float* lnb      = (const float*)d_in[10];
    const float* Wp       = (const float*)d_in[11];
    const float* bp       = (const float*)d_in[12];
    float* out = (float*)d_out;
    float* ws  = (float*)d_ws;

    // ---- workspace arena (float offsets; total 16,809,984 f = 67.2 MB) ----
    // A0 [0, 8388608): feat during scatter/recon; reused afterwards:
    float* feat = ws;
    unsigned short* Qbf   = (unsigned short*)ws;                 // 4,194,304 u16
    unsigned short* Kbf   = (unsigned short*)(ws + 2097152);     //   524,288 u16
    unsigned short* Vtb   = (unsigned short*)(ws + 2359296);     //   786,432 u16
    float*          confE = ws + 2752512;                        //     2,048 f
    unsigned short* wqb   = (unsigned short*)(ws + 2754560);     //    65,536 u16
    unsigned short* wkb   = (unsigned short*)(ws + 2787328);
    unsigned short* wvb   = (unsigned short*)(ws + 2820096);
    unsigned short* wpb   = (unsigned short*)(ws + 2852864);     //   196,608 u16
    float*          xsb   = ws + 2951168;                        //   524,288 f
    unsigned short* xsbf  = (unsigned short*)(ws + 3475456);     //   524,288 u16
    float*          vbuf  = ws + 3737600;                        //   524,288 f
    // A1 maskr
    float* maskr = ws + 8388608;                                 //    32,768 f
    // A2 [8421376, 14712832): apatch (first 4.2M f) -> aouts (6.29M f)
    unsigned short* apatch = (unsigned short*)(ws + 8421376);    // 8,388,608 u16
    unsigned short* aouts  = (unsigned short*)(ws + 8421376);    // 12,582,912 u16
    unsigned short* wTb    = (unsigned short*)(ws + 12615680);   // 1,048,576 u16 (dead before aouts written)
    // A3
    unsigned short* xbf = (unsigned short*)(ws + 14712832);      // 4,194,304 u16

    const float SC = 0.17677669529663687f * 1.4426950408889634f; // scale*log2e

    // zero scatter accumulators (feat + maskr adjacent)
    hipMemsetAsync(feat, 0, (size_t)(8388608 + 32768) * sizeof(float), stream);

    scatter_k  <<<16384, 256, 0, stream>>>(x_source, loc, feat, maskr);
    recon_fused<<<32768, 256, 0, stream>>>(feat, maskr, apatch);
    prep_misc  <<<10696, 256, 0, stream>>>(srw, x, Wq, Wk, Wv, Wp, conf, srb,
                                           wTb, xbf, wqb, wkb, wvb, wpb,
                                           confE, xsb);
    // conv as GEMM (2048 x 256 x 4096), split-K 16, atomic into bias-inited xsb
    bgemm<<<dim3(2, 16, 16), 256, 0, stream>>>(apatch, wTb, nullptr, xsb, nullptr,
                                               2048, 256, 4096, 16, 1, 0, 1.f);
    ln_k<<<2048, 256, 0, stream>>>(xsb, lnw, lnb, xsbf);
    // K = xs@Wk^T -> permuted bf16 [bh][1024][32]
    bgemm<<<dim3(2, 16, 1), 256, 0, stream>>>(xsbf, wkb, nullptr, nullptr, Kbf,
                                              2048, 256, 256, 1, 2, 10, 1.f);
    // V = xs@Wv^T -> fp32 vbuf
    bgemm<<<dim3(2, 16, 1), 256, 0, stream>>>(xsbf, wvb, nullptr, vbuf, nullptr,
                                              2048, 256, 256, 1, 0, 0, 1.f);
    // Q = x@Wq^T * scale*log2e -> permuted bf16 [bh][8192][32]
    bgemm<<<dim3(2, 128, 1), 256, 0, stream>>>(xbf, wqb, nullptr, nullptr, Qbf,
                                               16384, 256, 256, 1, 2, 13, SC);
    prep_vt<<<dim3(48, 16), 256, 0, stream>>>(vbuf, confE, Vtb);
    attn_v4<<<dim3(128, 16), 256, 0, stream>>>(Qbf, Kbf, Vtb, aouts);
    // final projection, fp32-accurate K-expansion split (K=768)
    bgemm<<<dim3(2, 128, 1), 256, 0, stream>>>(aouts, wpb, bp, out, nullptr,
                                               16384, 256, 768, 1, 0, 0, 1.f);
}

// Round 5
// 316.459 us; speedup vs baseline: 1.2213x; 1.2213x over previous
//
#include <hip/hip_runtime.h>
#include <hip/hip_bf16.h>
#include <cstddef>
#include <cstdint>

#define NTOK 8192      // N
#define CD   256       // C
#define HWPIX 16384    // H*W = 128*128
#define WIDTH 128
#define NSEQ 1024      // Ns

typedef __attribute__((ext_vector_type(8))) short bfrag;   // 8 bf16 = 4 VGPRs
typedef __attribute__((ext_vector_type(4))) float f32x4;

__device__ inline unsigned short f2bfu(float f) {
    __hip_bfloat16 h = __float2bfloat16(f);   // RTNE
    unsigned short u;
    __builtin_memcpy(&u, &h, 2);
    return u;
}
__device__ inline unsigned int rtn16(float f) {
    unsigned int u = __builtin_bit_cast(unsigned int, f);
    return u + 0x7fffu + ((u >> 16) & 1u);
}
__device__ inline float bits2f(unsigned int u) {
    return __builtin_bit_cast(float, u);
}
// async global -> LDS, 16 B per lane; lds base wave-uniform, HW adds lane*16
__device__ inline void gld16(const unsigned short* g, const unsigned short* l) {
    __builtin_amdgcn_global_load_lds(
        (const __attribute__((address_space(1))) unsigned int*)g,
        (__attribute__((address_space(3))) unsigned int*)l, 16, 0, 0);
}

// ---------------------------------------------------------------------------
// 1. token2map scatter
// ---------------------------------------------------------------------------
__global__ __launch_bounds__(256) void scatter_k(const float* __restrict__ xsrc,
        const float* __restrict__ loc, float* __restrict__ feat,
        float* __restrict__ maskr) {
    int token = blockIdx.x;
    int b = token >> 13;
    int c = threadIdx.x;
    float lx = loc[token * 2 + 0];
    float ly = loc[token * 2 + 1];
    lx = fminf(fmaxf(lx, 0.f), 1.f) * 127.0f;
    ly = fminf(fmaxf(ly, 0.f), 1.f) * 127.0f;
    int ix = __float2int_rn(lx);
    int iy = __float2int_rn(ly);
    int p = b * HWPIX + iy * WIDTH + ix;
    atomicAdd(&feat[(size_t)p * CD + c], xsrc[(size_t)token * CD + c]);
    if (c == 0) atomicAdd(&maskr[p], 1.0f);
}

// ---------------------------------------------------------------------------
// 2. fused normalize + 3x3 gaussian reconstruct + 4x4 patch gather -> bf16 A
// ---------------------------------------------------------------------------
__global__ __launch_bounds__(256) void recon_fused(const float* __restrict__ feat,
        const float* __restrict__ maskr, unsigned short* __restrict__ apatch) {
    __shared__ float sw[9];
    __shared__ float sgb[9];
    __shared__ int   snp[9];
    __shared__ float sci;
    __shared__ float sbc;
    int p = blockIdx.x;
    int b = p >> 14;
    int pix = p & 16383;
    int y = pix >> 7, x = pix & 127;
    int c = threadIdx.x;
    const float e1 = 0.882496902584595f;
    const float e2 = 0.778800783071405f;
    const float snorm = 1.0f / (1.0f + 4.0f * e1 + 4.0f * e2);
    if (c < 9) {
        int dy = c / 3 - 1, dx = c % 3 - 1;
        int yy = y + dy, xx = x + dx;
        bool valid = (yy >= 0 && yy <= 127 && xx >= 0 && xx <= 127);
        int np_ = valid ? (b * HWPIX + yy * WIDTH + xx) : p;
        int manh = (dy != 0) + (dx != 0);
        float g = ((manh == 2) ? e2 : (manh == 1) ? e1 : 1.0f) * snorm;
        float m = maskr[np_];
        float bin = (m > 0.f) ? 1.f : 0.f;
        float inv = 1.0f / (m + 1e-6f);
        float vb = valid ? bin : 0.f;
        sw[c]  = g * vb * inv;
        sgb[c] = g * vb;
        snp[c] = np_;
        if (c == 4) { sci = bin * inv; sbc = bin; }
    }
    __syncthreads();
    float gm = ((sgb[0] + sgb[1]) + (sgb[2] + sgb[3])) +
               ((sgb[4] + sgb[5]) + (sgb[6] + sgb[7])) + sgb[8];
    float gf = 0.f;
    #pragma unroll
    for (int j = 0; j < 9; j++)
        gf += sw[j] * feat[(size_t)snp[j] * CD + c];
    float f_int = (gm > 0.f) ? (gf / (gm + 1e-6f)) : 0.f;
    float fc = feat[(size_t)p * CD + c] * sci;
    float res = fc + (1.f - sbc) * f_int;
    int r = b * 1024 + (y >> 2) * 32 + (x >> 2);
    int k16 = (y & 3) * 4 + (x & 3);
    apatch[(size_t)r * 4096 + k16 * 256 + c] = f2bfu(res);
}

// ---------------------------------------------------------------------------
// 3. prep_misc (fused small prep), switched on blockIdx
// ---------------------------------------------------------------------------
__global__ __launch_bounds__(256) void prep_misc(
        const float* __restrict__ srw, const float* __restrict__ x,
        const float* __restrict__ Wq, const float* __restrict__ Wk,
        const float* __restrict__ Wv, const float* __restrict__ Wp,
        const float* __restrict__ srb,
        unsigned short* __restrict__ wTb, unsigned short* __restrict__ xbf,
        unsigned short* __restrict__ wqb, unsigned short* __restrict__ wkb,
        unsigned short* __restrict__ wvb, unsigned short* __restrict__ wpb,
        float* __restrict__ xsb) {
    int gid = blockIdx.x, tid = threadIdx.x;
    if (gid < 4096) {                       // sr_w transpose
        int idx = gid * 256 + tid;
        int co = idx >> 12;
        int rest = idx & 4095;
        int k16 = rest >> 8;
        int ci = rest & 255;
        int kh = k16 >> 2, kw = k16 & 3;
        wTb[idx] = f2bfu(srw[(size_t)co * 4096 + ci * 16 + kh * 4 + kw]);
    } else if (gid < 8384) {                // fp32 -> bf16 converts
        const float* s; unsigned short* d; int base;
        if (gid < 8192)      { s = x;  d = xbf; base = gid - 4096; }
        else if (gid < 8256) { s = Wq; d = wqb; base = gid - 8192; }
        else if (gid < 8320) { s = Wk; d = wkb; base = gid - 8256; }
        else                 { s = Wv; d = wvb; base = gid - 8320; }
        int i = (base * 256 + tid) * 4;
        float4 v = *(const float4*)(s + i);
        ushort4 o;
        o.x = f2bfu(v.x); o.y = f2bfu(v.y); o.z = f2bfu(v.z); o.w = f2bfu(v.w);
        *(ushort4*)(d + i) = o;
    } else if (gid < 8640) {                // Wp split [bh|bl|bh]
        int n = gid - 8384, t = tid;
        float w = Wp[n * 256 + t];
        unsigned short hu = f2bfu(w);
        float hf = bits2f(((unsigned int)hu) << 16);
        unsigned short lu = f2bfu(w - hf);
        wpb[n * 768 + t]       = hu;
        wpb[n * 768 + 256 + t] = lu;
        wpb[n * 768 + 512 + t] = hu;
    } else {                                // xsb init with bias
        int row = gid - 8640;
        xsb[(size_t)row * 256 + tid] = srb[tid];
    }
}

// ---------------------------------------------------------------------------
// 4. bf16 MFMA GEMM: 128x128 tile, 4 waves, BK=32.
//    mode 0: C fp32 = acc + bias[col]
//    mode 1: atomicAdd into C (split-K; C pre-initialized with bias)
//    mode 2: bf16 permuted write (Q): dstb[((b*8+h)<<13 | r)*32 + d] = acc*mult
//    mode 3: bf16 K write into STG tiles: row=(b*1024+key), col=(h*32+d):
//            dstb[((b*8+h)*16 + key/64)*5120 + (key%64)*40 + d]
// ---------------------------------------------------------------------------
__global__ __launch_bounds__(256) void bgemm(const unsigned short* __restrict__ A,
        const unsigned short* __restrict__ B, const float* __restrict__ bias,
        float* __restrict__ C, unsigned short* __restrict__ dstb,
        int M, int N, int K, int kSplit, int mode, float mult) {
    __shared__ __align__(16) unsigned short As[128 * 32];
    __shared__ __align__(16) unsigned short Bs[128 * 32];
    int tid = threadIdx.x;
    int wave = tid >> 6, lane = tid & 63, m15 = lane & 15, quad = lane >> 4;
    int wr = (wave >> 1) * 64, wc = (wave & 1) * 64;
    int m0 = blockIdx.y * 128, n0 = blockIdx.x * 128;
    int kchunk = K / kSplit, k0 = blockIdx.z * kchunk;
    int srow = tid >> 2, sko = (tid & 3) * 8;
    f32x4 acc[4][4];
    #pragma unroll
    for (int i = 0; i < 4; i++)
        #pragma unroll
        for (int j = 0; j < 4; j++) acc[i][j] = (f32x4){0.f, 0.f, 0.f, 0.f};
    const unsigned short* Ag = A + (size_t)(m0 + srow) * K + k0 + sko;
    const unsigned short* Bg = B + (size_t)(n0 + srow) * K + k0 + sko;
    for (int kk = 0; kk < kchunk; kk += 32) {
        bfrag a0 = *(const bfrag*)(Ag + kk);
        bfrag a1 = *(const bfrag*)(Ag + (size_t)64 * K + kk);
        bfrag b0 = *(const bfrag*)(Bg + kk);
        bfrag b1 = *(const bfrag*)(Bg + (size_t)64 * K + kk);
        __syncthreads();
        *(bfrag*)&As[srow * 32 + sko] = a0;
        *(bfrag*)&As[(srow + 64) * 32 + sko] = a1;
        *(bfrag*)&Bs[srow * 32 + sko] = b0;
        *(bfrag*)&Bs[(srow + 64) * 32 + sko] = b1;
        __syncthreads();
        bfrag af[4], bfr[4];
        #pragma unroll
        for (int mi = 0; mi < 4; mi++)
            af[mi] = *(const bfrag*)&As[(wr + mi * 16 + m15) * 32 + quad * 8];
        #pragma unroll
        for (int ni = 0; ni < 4; ni++)
            bfr[ni] = *(const bfrag*)&Bs[(wc + ni * 16 + m15) * 32 + quad * 8];
        #pragma unroll
        for (int mi = 0; mi < 4; mi++)
            #pragma unroll
            for (int ni = 0; ni < 4; ni++)
                acc[mi][ni] = __builtin_amdgcn_mfma_f32_16x16x32_bf16(
                                  af[mi], bfr[ni], acc[mi][ni], 0, 0, 0);
    }
    if (mode == 2) {
        #pragma unroll
        for (int mi = 0; mi < 4; mi++) {
            #pragma unroll
            for (int i = 0; i < 4; i++) {
                int row = m0 + wr + mi * 16 + quad * 4 + i;
                int b = row >> 13, r = row & 8191;
                #pragma unroll
                for (int ni = 0; ni < 4; ni++) {
                    int col = n0 + wc + ni * 16 + m15;
                    int h = col >> 5, d = col & 31;
                    size_t di = ((((size_t)(b * 8 + h)) << 13) + r) * 32 + d;
                    dstb[di] = f2bfu(acc[mi][ni][i] * mult);
                }
            }
        }
    } else if (mode == 3) {
        #pragma unroll
        for (int mi = 0; mi < 4; mi++) {
            #pragma unroll
            for (int i = 0; i < 4; i++) {
                int row = m0 + wr + mi * 16 + quad * 4 + i;
                int b = row >> 10, key = row & 1023;
                int tile = key >> 6, rin = key & 63;
                #pragma unroll
                for (int ni = 0; ni < 4; ni++) {
                    int col = n0 + wc + ni * 16 + m15;
                    int h = col >> 5, d = col & 31;
                    size_t di = ((size_t)((b * 8 + h) * 16 + tile)) * 5120
                                + rin * 40 + d;
                    dstb[di] = f2bfu(acc[mi][ni][i]);
                }
            }
        }
    } else {
        #pragma unroll
        for (int mi = 0; mi < 4; mi++) {
            #pragma unroll
            for (int i = 0; i < 4; i++) {
                size_t row = (size_t)(m0 + wr + mi * 16 + quad * 4 + i) * N;
                #pragma unroll
                for (int ni = 0; ni < 4; ni++) {
                    int col = n0 + wc + ni * 16 + m15;
                    float v = acc[mi][ni][i];
                    if (mode == 1) atomicAdd(&C[row + col], v);
                    else C[row + col] = v + (bias ? bias[col] : 0.f);
                }
            }
        }
    }
}

// ---------------------------------------------------------------------------
// 5. LayerNorm (C=256), fp32 in -> bf16 out
// ---------------------------------------------------------------------------
__global__ __launch_bounds__(256) void ln_k(const float* __restrict__ xs,
        const float* __restrict__ w, const float* __restrict__ bvec,
        unsigned short* __restrict__ outb) {
    int row = blockIdx.x;
    int c = threadIdx.x;
    float v = xs[(size_t)row * 256 + c];
    __shared__ float red[4];
    float s = v;
    #pragma unroll
    for (int o = 32; o >= 1; o >>= 1) s += __shfl_down(s, o, 64);
    if ((c & 63) == 0) red[c >> 6] = s;
    __syncthreads();
    float mean = (red[0] + red[1] + red[2] + red[3]) * (1.f / 256.f);
    __syncthreads();
    float d = v - mean;
    float s2 = d * d;
    #pragma unroll
    for (int o = 32; o >= 1; o >>= 1) s2 += __shfl_down(s2, o, 64);
    if ((c & 63) == 0) red[c >> 6] = s2;
    __syncthreads();
    float var = (red[0] + red[1] + red[2] + red[3]) * (1.f / 256.f);
    float r = 1.0f / sqrtf(var + 1e-5f);
    outb[(size_t)row * 256 + c] = f2bfu(d * r * w[c] + bvec[c]);
}

// ---------------------------------------------------------------------------
// 6. prep_vt: fill STG tile V'-part (32 d-rows x 64 permuted keys, stride 72)
//    and stow cf = conf*log2e into the K-row pads (u16 offset 32 of each row).
//    STG tile layout (u16): [0,2560): K 64 rows x 40 (d0..31, cf fp32 @32);
//                           [2560,4864): V' 32 rows x 72; [4864,5120) pad.
// ---------------------------------------------------------------------------
__global__ __launch_bounds__(256) void prep_vt(const float* __restrict__ vbuf,
        const float* __restrict__ conf, unsigned short* __restrict__ stg) {
    int tile = blockIdx.x;             // 0..15
    int bh = blockIdx.y;               // 0..15
    int b = bh >> 3, h = bh & 7;
    int t = threadIdx.x;
    unsigned short* base = stg + ((size_t)bh * 16 + tile) * 5120;
    int row = t >> 3, kq = t & 7;      // d-row 0..31, 8 cols each
    unsigned short o[8];
    #pragma unroll
    for (int j = 0; j < 8; j++) {
        int col = kq * 8 + j;
        int key = tile * 64 + (col >> 2) + (col & 3) * 16;   // perm: col=4m+sub
        o[j] = f2bfu(vbuf[((size_t)(b * NSEQ + key)) * 256 + h * 32 + row]);
    }
    ushort4 lo, hi;
    lo.x = o[0]; lo.y = o[1]; lo.z = o[2]; lo.w = o[3];
    hi.x = o[4]; hi.y = o[5]; hi.z = o[6]; hi.w = o[7];
    *(ushort4*)&base[2560 + row * 72 + kq * 8]     = lo;
    *(ushort4*)&base[2560 + row * 72 + kq * 8 + 4] = hi;
    if (t < 64) {
        float cfv = conf[b * NSEQ + tile * 64 + t] * 1.4426950408889634f;
        *(float*)&base[t * 40 + 32] = cfv;
    }
}

// ---------------------------------------------------------------------------
// 7. MFMA flash attention v5: 32 q-rows/wave (v3 density), block-cooperative
//    async LDS staging of K+cf+V' tiles (global_load_lds, dbuf), prefetch
//    issued before compute so it overlaps the whole tile body. One barrier
//    per tile. No running max (logits bounded).
// ---------------------------------------------------------------------------
__global__ __launch_bounds__(256, 4) void attn_v5(
        const unsigned short* __restrict__ Qb,   // [bh][8192][32] *scale*log2e
        const unsigned short* __restrict__ STG,  // [bh][16][5120 u16]
        unsigned short* __restrict__ aout) {     // [16384][768] hi|hi|lo
    __shared__ __align__(16) unsigned short SB[2][5120];
    __shared__ __align__(16) unsigned short Pl[4][2304];
    int tid  = threadIdx.x;
    int wave = tid >> 6;
    int lane = tid & 63;
    int m15  = lane & 15;
    int quad = lane >> 4;
    int bh = blockIdx.y;
    int b  = bh >> 3;
    int h  = bh & 7;
    int qbase = blockIdx.x * 128 + wave * 32;

    const unsigned short* qp = Qb + ((size_t)bh * NTOK + qbase) * 32;
    bfrag Qa0 = *(const bfrag*)(qp + m15 * 32 + quad * 8);
    bfrag Qa1 = *(const bfrag*)(qp + (16 + m15) * 32 + quad * 8);
    const unsigned short* sg = STG + (size_t)bh * 16 * 5120;
    unsigned short* Pw = Pl[wave];

    f32x4 O[2][2];
    float lrow[2][4];
    #pragma unroll
    for (int t = 0; t < 2; t++) {
        #pragma unroll
        for (int dt = 0; dt < 2; dt++) O[t][dt] = (f32x4){0.f, 0.f, 0.f, 0.f};
        #pragma unroll
        for (int r = 0; r < 4; r++) lrow[t][r] = 0.f;
    }
    f32x4 zero = (f32x4){0.f, 0.f, 0.f, 0.f};

    // stage tile 0: 10240 B = 10 chunks of 1 KB; wave w: chunks w, w+4;
    // waves 0,1 also take chunks 8,9 (all branches wave-uniform)
    {
        const unsigned short* g = sg;
        unsigned short* l = SB[0];
        gld16(g + wave * 512 + lane * 8, l + wave * 512);
        gld16(g + (wave + 4) * 512 + lane * 8, l + (wave + 4) * 512);
        if (wave < 2) gld16(g + (8 + wave) * 512 + lane * 8, l + (8 + wave) * 512);
    }
    __syncthreads();

    for (int t = 0; t < 16; t++) {
        const unsigned short* Ks = SB[t & 1];
        const unsigned short* Vs = Ks + 2560;
        // ---- frag loads from LDS into regs ----
        bfrag kf[4]; float cf[4]; bfrag vfr[2][2];
        #pragma unroll
        for (int sub = 0; sub < 4; sub++) {
            kf[sub] = *(const bfrag*)&Ks[(sub * 16 + m15) * 40 + quad * 8];
            cf[sub] = *(const float*)&Ks[(sub * 16 + m15) * 40 + 32];
        }
        #pragma unroll
        for (int kf2 = 0; kf2 < 2; kf2++)
            #pragma unroll
            for (int dt = 0; dt < 2; dt++)
                vfr[kf2][dt] = *(const bfrag*)&Vs[(dt * 16 + m15) * 72 +
                                                  kf2 * 32 + quad * 8];
        // ---- issue async prefetch of tile t+1 (overlaps compute below) ----
        if (t < 15) {
            const unsigned short* g = sg + (size_t)(t + 1) * 5120;
            unsigned short* l = SB[(t + 1) & 1];
            gld16(g + wave * 512 + lane * 8, l + wave * 512);
            gld16(g + (wave + 4) * 512 + lane * 8, l + (wave + 4) * 512);
            if (wave < 2) gld16(g + (8 + wave) * 512 + lane * 8,
                                l + (8 + wave) * 512);
        }
        // ---- S = Q K^T (8 MFMAs) ----
        f32x4 S[2][4];
        #pragma unroll
        for (int sub = 0; sub < 4; sub++) {
            S[0][sub] = __builtin_amdgcn_mfma_f32_16x16x32_bf16(Qa0, kf[sub], zero, 0, 0, 0);
            S[1][sub] = __builtin_amdgcn_mfma_f32_16x16x32_bf16(Qa1, kf[sub], zero, 0, 0, 0);
        }
        // ---- P = exp2(S + cf); pack into permuted cols; accumulate l ----
        #pragma unroll
        for (int tq = 0; tq < 2; tq++) {
            #pragma unroll
            for (int r = 0; r < 4; r++) {
                float2 p01, p23;
                p01.x = exp2f(S[tq][0][r] + cf[0]);
                p01.y = exp2f(S[tq][1][r] + cf[1]);
                p23.x = exp2f(S[tq][2][r] + cf[2]);
                p23.y = exp2f(S[tq][3][r] + cf[3]);
                lrow[tq][r] += (p01.x + p01.y) + (p23.x + p23.y);
                __hip_bfloat162 q01 = __float22bfloat162_rn(p01);
                __hip_bfloat162 q23 = __float22bfloat162_rn(p23);
                uint2 dd;
                __builtin_memcpy(&dd.x, &q01, 4);
                __builtin_memcpy(&dd.y, &q23, 4);
                *(uint2*)&Pw[tq * 1152 + (quad * 4 + r) * 72 + 4 * m15] = dd;
            }
        }
        // ---- O += P V' (8 MFMAs) ----
        #pragma unroll
        for (int kf2 = 0; kf2 < 2; kf2++) {
            bfrag Pa0 = *(const bfrag*)&Pw[0 * 1152 + m15 * 72 + kf2 * 32 + quad * 8];
            bfrag Pa1 = *(const bfrag*)&Pw[1 * 1152 + m15 * 72 + kf2 * 32 + quad * 8];
            #pragma unroll
            for (int dt = 0; dt < 2; dt++) {
                O[0][dt] = __builtin_amdgcn_mfma_f32_16x16x32_bf16(Pa0, vfr[kf2][dt], O[0][dt], 0, 0, 0);
                O[1][dt] = __builtin_amdgcn_mfma_f32_16x16x32_bf16(Pa1, vfr[kf2][dt], O[1][dt], 0, 0, 0);
            }
        }
        __syncthreads();   // drains prefetch (vmcnt) + all waves done with bufs
    }
    // ---- reduce lrow over the 16 key-lanes ----
    #pragma unroll
    for (int tq = 0; tq < 2; tq++) {
        #pragma unroll
        for (int r = 0; r < 4; r++) {
            float s = lrow[tq][r];
            s += __shfl_xor(s, 1, 64);
            s += __shfl_xor(s, 2, 64);
            s += __shfl_xor(s, 4, 64);
            s += __shfl_xor(s, 8, 64);
            lrow[tq][r] = s;
        }
    }
    // ---- epilogue: O/l -> split hi/hi/lo bf16 into aout [16384][768] ----
    #pragma unroll
    for (int tq = 0; tq < 2; tq++) {
        #pragma unroll
        for (int r = 0; r < 4; r++) {
            float inv = 1.0f / lrow[tq][r];
            int row = b * NTOK + qbase + tq * 16 + quad * 4 + r;
            size_t rb = (size_t)row * 768;
            #pragma unroll
            for (int dt = 0; dt < 2; dt++) {
                float o = O[tq][dt][r] * inv;
                unsigned int hr = rtn16(o);
                unsigned short hu = hr >> 16;
                float hf = bits2f(hr & 0xffff0000u);
                unsigned short lu = rtn16(o - hf) >> 16;
                int col = h * 32 + dt * 16 + m15;
                aout[rb + col]       = hu;
                aout[rb + 256 + col] = hu;
                aout[rb + 512 + col] = lu;
            }
        }
    }
}

// ---------------------------------------------------------------------------
extern "C" void kernel_launch(void* const* d_in, const int* in_sizes, int n_in,
                              void* d_out, int out_size, void* d_ws, size_t ws_size,
                              hipStream_t stream) {
    const float* x        = (const float*)d_in[0];
    const float* x_source = (const float*)d_in[1];
    const float* loc      = (const float*)d_in[2];
    const float* conf     = (const float*)d_in[3];
    const float* Wq       = (const float*)d_in[4];
    const float* Wk       = (const float*)d_in[5];
    const float* Wv       = (const float*)d_in[6];
    const float* srw      = (const float*)d_in[7];
    const float* srb      = (const float*)d_in[8];
    const float* lnw      = (const float*)d_in[9];
    const float* lnb      = (const float*)d_in[10];
    const float* Wp       = (const float*)d_in[11];
    const float* bp       = (const float*)d_in[12];
    float* out = (float*)d_out;
    float* ws  = (float*)d_ws;

    // ---- workspace arena (float offsets) ----
    // A0 [0, 8388608): feat during scatter/recon; reused afterwards:
    float* feat = ws;
    unsigned short* Qbf = (unsigned short*)ws;                  // 4,194,304 u16
    unsigned short* stg = (unsigned short*)(ws + 2097152);      // 1,310,720 u16
    unsigned short* wqb = (unsigned short*)(ws + 2752512);      //    65,536 u16
    unsigned short* wkb = (unsigned short*)(ws + 2785280);
    unsigned short* wvb = (unsigned short*)(ws + 2818048);
    unsigned short* wpb = (unsigned short*)(ws + 2850816);      //   196,608 u16
    float*          xsb  = ws + 2949120;                        //   524,288 f
    unsigned short* xsbf = (unsigned short*)(ws + 3473408);     //   524,288 u16
    float*          vbuf = ws + 3735552;                        //   524,288 f
    // A1 maskr
    float* maskr = ws + 8388608;                                //    32,768 f
    // A2 [8421376, 14712832): apatch -> aouts overlay; wTb inside (dead early)
    unsigned short* apatch = (unsigned short*)(ws + 8421376);   // 8,388,608 u16
    unsigned short* aouts  = (unsigned short*)(ws + 8421376);   // 12,582,912 u16
    unsigned short* wTb    = (unsigned short*)(ws + 12615680);  // 1,048,576 u16
    // A3
    unsigned short* xbf = (unsigned short*)(ws + 14712832);     // 4,194,304 u16

    const float SC = 0.17677669529663687f * 1.4426950408889634f; // scale*log2e

    hipMemsetAsync(feat, 0, (size_t)(8388608 + 32768) * sizeof(float), stream);

    scatter_k  <<<16384, 256, 0, stream>>>(x_source, loc, feat, maskr);
    recon_fused<<<32768, 256, 0, stream>>>(feat, maskr, apatch);
    prep_misc  <<<10688, 256, 0, stream>>>(srw, x, Wq, Wk, Wv, Wp, srb,
                                           wTb, xbf, wqb, wkb, wvb, wpb, xsb);
    // conv as GEMM (2048 x 256 x 4096), split-K 16, atomic into bias-inited xsb
    bgemm<<<dim3(2, 16, 16), 256, 0, stream>>>(apatch, wTb, nullptr, xsb, nullptr,
                                               2048, 256, 4096, 16, 1, 1.f);
    ln_k<<<2048, 256, 0, stream>>>(xsb, lnw, lnb, xsbf);
    // K = xs@Wk^T -> STG K-part (tile-contiguous, padded rows, cf pads later)
    bgemm<<<dim3(2, 16, 1), 256, 0, stream>>>(xsbf, wkb, nullptr, nullptr, stg,
                                              2048, 256, 256, 1, 3, 1.f);
    // V = xs@Wv^T -> fp32 vbuf
    bgemm<<<dim3(2, 16, 1), 256, 0, stream>>>(xsbf, wvb, nullptr, vbuf, nullptr,
                                              2048, 256, 256, 1, 0, 1.f);
    // Q = x@Wq^T * scale*log2e -> permuted bf16 [bh][8192][32]
    bgemm<<<dim3(2, 128, 1), 256, 0, stream>>>(xbf, wqb, nullptr, nullptr, Qbf,
                                               16384, 256, 256, 1, 2, SC);
    prep_vt<<<dim3(16, 16), 256, 0, stream>>>(vbuf, conf, stg);
    attn_v5<<<dim3(64, 16), 256, 0, stream>>>(Qbf, stg, aouts);
    // final projection, fp32-accurate K-expansion split (K=768)
    bgemm<<<dim3(2, 128, 1), 256, 0, stream>>>(aouts, wpb, bp, out, nullptr,
                                               16384, 256, 768, 1, 0, 1.f);
}

// Round 6
// 297.462 us; speedup vs baseline: 1.2993x; 1.0639x over previous
//
#include <hip/hip_runtime.h>
#include <hip/hip_bf16.h>
#include <cstddef>
#include <cstdint>

#define NTOK 8192      // N
#define CD   256       // C
#define HWPIX 16384    // H*W = 128*128
#define WIDTH 128
#define NSEQ 1024      // Ns

typedef __attribute__((ext_vector_type(8))) short bfrag;   // 8 bf16 = 4 VGPRs
typedef __attribute__((ext_vector_type(4))) float f32x4;

__device__ inline unsigned short f2bfu(float f) {
    __hip_bfloat16 h = __float2bfloat16(f);   // RTNE
    unsigned short u;
    __builtin_memcpy(&u, &h, 2);
    return u;
}
__device__ inline unsigned int rtn16(float f) {
    unsigned int u = __builtin_bit_cast(unsigned int, f);
    return u + 0x7fffu + ((u >> 16) & 1u);
}
__device__ inline float bits2f(unsigned int u) {
    return __builtin_bit_cast(float, u);
}
__device__ inline bfrag cvt8(float4 a, float4 b) {
    bfrag r;
    r[0] = (short)f2bfu(a.x); r[1] = (short)f2bfu(a.y);
    r[2] = (short)f2bfu(a.z); r[3] = (short)f2bfu(a.w);
    r[4] = (short)f2bfu(b.x); r[5] = (short)f2bfu(b.y);
    r[6] = (short)f2bfu(b.z); r[7] = (short)f2bfu(b.w);
    return r;
}
// async global -> LDS, 16 B per lane; lds base wave-uniform, HW adds lane*16
__device__ inline void gld16(const unsigned short* g, const unsigned short* l) {
    __builtin_amdgcn_global_load_lds(
        (const __attribute__((address_space(1))) unsigned int*)g,
        (__attribute__((address_space(3))) unsigned int*)l, 16, 0, 0);
}

// ---------------------------------------------------------------------------
// 1. token2map scatter
// ---------------------------------------------------------------------------
__global__ __launch_bounds__(256) void scatter_k(const float* __restrict__ xsrc,
        const float* __restrict__ loc, float* __restrict__ feat,
        float* __restrict__ maskr) {
    int token = blockIdx.x;
    int b = token >> 13;
    int c = threadIdx.x;
    float lx = loc[token * 2 + 0];
    float ly = loc[token * 2 + 1];
    lx = fminf(fmaxf(lx, 0.f), 1.f) * 127.0f;
    ly = fminf(fmaxf(ly, 0.f), 1.f) * 127.0f;
    int ix = __float2int_rn(lx);
    int iy = __float2int_rn(ly);
    int p = b * HWPIX + iy * WIDTH + ix;
    atomicAdd(&feat[(size_t)p * CD + c], xsrc[(size_t)token * CD + c]);
    if (c == 0) atomicAdd(&maskr[p], 1.0f);
}

// ---------------------------------------------------------------------------
// 2. fused normalize + 3x3 gaussian reconstruct + 4x4 patch gather -> bf16 A
// ---------------------------------------------------------------------------
__global__ __launch_bounds__(256) void recon_fused(const float* __restrict__ feat,
        const float* __restrict__ maskr, unsigned short* __restrict__ apatch) {
    __shared__ float sw[9];
    __shared__ float sgb[9];
    __shared__ int   snp[9];
    __shared__ float sci;
    __shared__ float sbc;
    int p = blockIdx.x;
    int b = p >> 14;
    int pix = p & 16383;
    int y = pix >> 7, x = pix & 127;
    int c = threadIdx.x;
    const float e1 = 0.882496902584595f;
    const float e2 = 0.778800783071405f;
    const float snorm = 1.0f / (1.0f + 4.0f * e1 + 4.0f * e2);
    if (c < 9) {
        int dy = c / 3 - 1, dx = c % 3 - 1;
        int yy = y + dy, xx = x + dx;
        bool valid = (yy >= 0 && yy <= 127 && xx >= 0 && xx <= 127);
        int np_ = valid ? (b * HWPIX + yy * WIDTH + xx) : p;
        int manh = (dy != 0) + (dx != 0);
        float g = ((manh == 2) ? e2 : (manh == 1) ? e1 : 1.0f) * snorm;
        float m = maskr[np_];
        float bin = (m > 0.f) ? 1.f : 0.f;
        float inv = 1.0f / (m + 1e-6f);
        float vb = valid ? bin : 0.f;
        sw[c]  = g * vb * inv;
        sgb[c] = g * vb;
        snp[c] = np_;
        if (c == 4) { sci = bin * inv; sbc = bin; }
    }
    __syncthreads();
    float gm = ((sgb[0] + sgb[1]) + (sgb[2] + sgb[3])) +
               ((sgb[4] + sgb[5]) + (sgb[6] + sgb[7])) + sgb[8];
    float gf = 0.f;
    #pragma unroll
    for (int j = 0; j < 9; j++)
        gf += sw[j] * feat[(size_t)snp[j] * CD + c];
    float f_int = (gm > 0.f) ? (gf / (gm + 1e-6f)) : 0.f;
    float fc = feat[(size_t)p * CD + c] * sci;
    float res = fc + (1.f - sbc) * f_int;
    int r = b * 1024 + (y >> 2) * 32 + (x >> 2);
    int k16 = (y & 3) * 4 + (x & 3);
    apatch[(size_t)r * 4096 + k16 * 256 + c] = f2bfu(res);
}

// ---------------------------------------------------------------------------
// 3. prep_misc (fused small prep), switched on blockIdx:
//    [0,4096)      wtrans  srw -> wTb
//    [4096,4288)   cvt Wq/Wk/Wv -> wqb/wkb/wvb (wkb,wvb adjacent = B of KV)
//    [4288,4544)   Wp split [bh|bl|bh]
//    [4544,4552)   cf = conf*log2e into STG K-row pads (all 8 heads)
//    [4552,6600)   xsb init with srb (conv split-K accumulator)
// ---------------------------------------------------------------------------
__global__ __launch_bounds__(256) void prep_misc(
        const float* __restrict__ srw, const float* __restrict__ Wq,
        const float* __restrict__ Wk, const float* __restrict__ Wv,
        const float* __restrict__ Wp, const float* __restrict__ conf,
        const float* __restrict__ srb,
        unsigned short* __restrict__ wTb, unsigned short* __restrict__ wqb,
        unsigned short* __restrict__ wkb, unsigned short* __restrict__ wvb,
        unsigned short* __restrict__ wpb, unsigned short* __restrict__ stg,
        float* __restrict__ xsb) {
    int gid = blockIdx.x, tid = threadIdx.x;
    if (gid < 4096) {                       // sr_w transpose
        int idx = gid * 256 + tid;
        int co = idx >> 12;
        int rest = idx & 4095;
        int k16 = rest >> 8;
        int ci = rest & 255;
        int kh = k16 >> 2, kw = k16 & 3;
        wTb[idx] = f2bfu(srw[(size_t)co * 4096 + ci * 16 + kh * 4 + kw]);
    } else if (gid < 4288) {                // weight fp32 -> bf16
        const float* s; unsigned short* d; int base;
        if (gid < 4160)      { s = Wq; d = wqb; base = gid - 4096; }
        else if (gid < 4224) { s = Wk; d = wkb; base = gid - 4160; }
        else                 { s = Wv; d = wvb; base = gid - 4224; }
        int i = (base * 256 + tid) * 4;
        float4 v = *(const float4*)(s + i);
        ushort4 o;
        o.x = f2bfu(v.x); o.y = f2bfu(v.y); o.z = f2bfu(v.z); o.w = f2bfu(v.w);
        *(ushort4*)(d + i) = o;
    } else if (gid < 4544) {                // Wp split [bh|bl|bh]
        int n = gid - 4288, t = tid;
        float w = Wp[n * 256 + t];
        unsigned short hu = f2bfu(w);
        float hf = bits2f(((unsigned int)hu) << 16);
        unsigned short lu = f2bfu(w - hf);
        wpb[n * 768 + t]       = hu;
        wpb[n * 768 + 256 + t] = lu;
        wpb[n * 768 + 512 + t] = hu;
    } else if (gid < 4552) {                // cf pads into STG
        int idx = (gid - 4544) * 256 + tid;  // b*1024 + key
        int b = idx >> 10, key = idx & 1023;
        int tile = key >> 6, rin = key & 63;
        float val = conf[idx] * 1.4426950408889634f;
        #pragma unroll
        for (int h = 0; h < 8; h++)
            *(float*)&stg[((size_t)((b * 8 + h) * 16 + tile)) * 5120
                          + rin * 40 + 32] = val;
    } else {                                // xsb init with bias
        int row = gid - 4552;
        xsb[(size_t)row * 256 + tid] = srb[tid];
    }
}

// ---------------------------------------------------------------------------
// 4. bf16 MFMA GEMM: 128x128 tile, 4 waves, BK=32. A bf16 (or fp32 if Af set).
//    mode 0: C fp32 = acc + bias[col]
//    mode 1: atomicAdd into C (split-K; C pre-initialized with bias)
//    mode 2: bf16 permuted write (Q): dstb[((b*8+h)<<13 | r)*32 + d] = acc*mult
//    mode 3: KV fused -> STG tiles. col<256: K bf16 at [tile]*5120+rin*40+d.
//            col>=256: V' bf16 permuted at [tile]*5120+2560+d*72+(4*m+sub).
// ---------------------------------------------------------------------------
__global__ __launch_bounds__(256) void bgemm(const unsigned short* __restrict__ A,
        const float* __restrict__ Af, const unsigned short* __restrict__ B,
        const float* __restrict__ bias, float* __restrict__ C,
        unsigned short* __restrict__ dstb,
        int M, int N, int K, int kSplit, int mode, float mult) {
    __shared__ __align__(16) unsigned short As[128 * 32];
    __shared__ __align__(16) unsigned short Bs[128 * 32];
    int tid = threadIdx.x;
    int wave = tid >> 6, lane = tid & 63, m15 = lane & 15, quad = lane >> 4;
    int wr = (wave >> 1) * 64, wc = (wave & 1) * 64;
    int m0 = blockIdx.y * 128, n0 = blockIdx.x * 128;
    int kchunk = K / kSplit, k0 = blockIdx.z * kchunk;
    int srow = tid >> 2, sko = (tid & 3) * 8;
    f32x4 acc[4][4];
    #pragma unroll
    for (int i = 0; i < 4; i++)
        #pragma unroll
        for (int j = 0; j < 4; j++) acc[i][j] = (f32x4){0.f, 0.f, 0.f, 0.f};
    const unsigned short* Ag = A + (size_t)(m0 + srow) * K + k0 + sko;
    const float* Afg = Af + (size_t)(m0 + srow) * K + k0 + sko;
    const unsigned short* Bg = B + (size_t)(n0 + srow) * K + k0 + sko;
    for (int kk = 0; kk < kchunk; kk += 32) {
        bfrag a0, a1;
        if (Af) {
            float4 f0 = *(const float4*)(Afg + kk);
            float4 f1 = *(const float4*)(Afg + kk + 4);
            float4 f2 = *(const float4*)(Afg + (size_t)64 * K + kk);
            float4 f3 = *(const float4*)(Afg + (size_t)64 * K + kk + 4);
            a0 = cvt8(f0, f1);
            a1 = cvt8(f2, f3);
        } else {
            a0 = *(const bfrag*)(Ag + kk);
            a1 = *(const bfrag*)(Ag + (size_t)64 * K + kk);
        }
        bfrag b0 = *(const bfrag*)(Bg + kk);
        bfrag b1 = *(const bfrag*)(Bg + (size_t)64 * K + kk);
        __syncthreads();
        *(bfrag*)&As[srow * 32 + sko] = a0;
        *(bfrag*)&As[(srow + 64) * 32 + sko] = a1;
        *(bfrag*)&Bs[srow * 32 + sko] = b0;
        *(bfrag*)&Bs[(srow + 64) * 32 + sko] = b1;
        __syncthreads();
        bfrag af[4], bfr[4];
        #pragma unroll
        for (int mi = 0; mi < 4; mi++)
            af[mi] = *(const bfrag*)&As[(wr + mi * 16 + m15) * 32 + quad * 8];
        #pragma unroll
        for (int ni = 0; ni < 4; ni++)
            bfr[ni] = *(const bfrag*)&Bs[(wc + ni * 16 + m15) * 32 + quad * 8];
        #pragma unroll
        for (int mi = 0; mi < 4; mi++)
            #pragma unroll
            for (int ni = 0; ni < 4; ni++)
                acc[mi][ni] = __builtin_amdgcn_mfma_f32_16x16x32_bf16(
                                  af[mi], bfr[ni], acc[mi][ni], 0, 0, 0);
    }
    if (mode == 2) {
        #pragma unroll
        for (int mi = 0; mi < 4; mi++) {
            #pragma unroll
            for (int i = 0; i < 4; i++) {
                int row = m0 + wr + mi * 16 + quad * 4 + i;
                int b = row >> 13, r = row & 8191;
                #pragma unroll
                for (int ni = 0; ni < 4; ni++) {
                    int col = n0 + wc + ni * 16 + m15;
                    int h = col >> 5, d = col & 31;
                    size_t di = ((((size_t)(b * 8 + h)) << 13) + r) * 32 + d;
                    dstb[di] = f2bfu(acc[mi][ni][i] * mult);
                }
            }
        }
    } else if (mode == 3) {
        #pragma unroll
        for (int mi = 0; mi < 4; mi++) {
            #pragma unroll
            for (int i = 0; i < 4; i++) {
                int row = m0 + wr + mi * 16 + quad * 4 + i;
                int b = row >> 10, key = row & 1023;
                int tile = key >> 6, rin = key & 63;
                #pragma unroll
                for (int ni = 0; ni < 4; ni++) {
                    int col = n0 + wc + ni * 16 + m15;
                    unsigned short v = f2bfu(acc[mi][ni][i]);
                    if (col < 256) {        // K part
                        int h = col >> 5, d = col & 31;
                        size_t di = ((size_t)((b * 8 + h) * 16 + tile)) * 5120
                                    + rin * 40 + d;
                        dstb[di] = v;
                    } else {                // V' part (permuted transpose)
                        int c2 = col - 256;
                        int h = c2 >> 5, d = c2 & 31;
                        int m = rin & 15, sub = rin >> 4;
                        size_t di = ((size_t)((b * 8 + h) * 16 + tile)) * 5120
                                    + 2560 + d * 72 + 4 * m + sub;
                        dstb[di] = v;
                    }
                }
            }
        }
    } else {
        #pragma unroll
        for (int mi = 0; mi < 4; mi++) {
            #pragma unroll
            for (int i = 0; i < 4; i++) {
                size_t row = (size_t)(m0 + wr + mi * 16 + quad * 4 + i) * N;
                #pragma unroll
                for (int ni = 0; ni < 4; ni++) {
                    int col = n0 + wc + ni * 16 + m15;
                    float v = acc[mi][ni][i];
                    if (mode == 1) atomicAdd(&C[row + col], v);
                    else C[row + col] = v + (bias ? bias[col] : 0.f);
                }
            }
        }
    }
}

// ---------------------------------------------------------------------------
// 5. LayerNorm (C=256), fp32 in -> bf16 out
// ---------------------------------------------------------------------------
__global__ __launch_bounds__(256) void ln_k(const float* __restrict__ xs,
        const float* __restrict__ w, const float* __restrict__ bvec,
        unsigned short* __restrict__ outb) {
    int row = blockIdx.x;
    int c = threadIdx.x;
    float v = xs[(size_t)row * 256 + c];
    __shared__ float red[4];
    float s = v;
    #pragma unroll
    for (int o = 32; o >= 1; o >>= 1) s += __shfl_down(s, o, 64);
    if ((c & 63) == 0) red[c >> 6] = s;
    __syncthreads();
    float mean = (red[0] + red[1] + red[2] + red[3]) * (1.f / 256.f);
    __syncthreads();
    float d = v - mean;
    float s2 = d * d;
    #pragma unroll
    for (int o = 32; o >= 1; o >>= 1) s2 += __shfl_down(s2, o, 64);
    if ((c & 63) == 0) red[c >> 6] = s2;
    __syncthreads();
    float var = (red[0] + red[1] + red[2] + red[3]) * (1.f / 256.f);
    float r = 1.0f / sqrtf(var + 1e-5f);
    outb[(size_t)row * 256 + c] = f2bfu(d * r * w[c] + bvec[c]);
}

// ---------------------------------------------------------------------------
// 6. MFMA flash attention v6: 32 q-rows/wave, block-cooperative async LDS
//    staging (dbuf, prefetch issued at top of tile), cf folded into the QK
//    MFMA C-operand, manual RTNE bf16 pair-pack. One barrier per tile.
// ---------------------------------------------------------------------------
__global__ __launch_bounds__(256, 4) void attn_v6(
        const unsigned short* __restrict__ Qb,   // [bh][8192][32] *scale*log2e
        const unsigned short* __restrict__ STG,  // [bh][16][5120 u16]
        unsigned short* __restrict__ aout) {     // [16384][768] hi|hi|lo
    __shared__ __align__(16) unsigned short SB[2][5120];
    __shared__ __align__(16) unsigned short Pl[4][2304];
    int tid  = threadIdx.x;
    int wave = tid >> 6;
    int lane = tid & 63;
    int m15  = lane & 15;
    int quad = lane >> 4;
    int bh = blockIdx.y;
    int b  = bh >> 3;
    int h  = bh & 7;
    int qbase = blockIdx.x * 128 + wave * 32;

    const unsigned short* qp = Qb + ((size_t)bh * NTOK + qbase) * 32;
    bfrag Qa0 = *(const bfrag*)(qp + m15 * 32 + quad * 8);
    bfrag Qa1 = *(const bfrag*)(qp + (16 + m15) * 32 + quad * 8);
    const unsigned short* sg = STG + (size_t)bh * 16 * 5120;
    unsigned short* Pw = Pl[wave];

    f32x4 O[2][2];
    float lrow[2][4];
    #pragma unroll
    for (int t = 0; t < 2; t++) {
        #pragma unroll
        for (int dt = 0; dt < 2; dt++) O[t][dt] = (f32x4){0.f, 0.f, 0.f, 0.f};
        #pragma unroll
        for (int r = 0; r < 4; r++) lrow[t][r] = 0.f;
    }

    // stage tile 0: 10240 B = 10 chunks of 1 KB; wave w: chunks w, w+4;
    // waves 0,1 also take chunks 8,9 (wave-uniform branches)
    {
        const unsigned short* g = sg;
        unsigned short* l = SB[0];
        gld16(g + wave * 512 + lane * 8, l + wave * 512);
        gld16(g + (wave + 4) * 512 + lane * 8, l + (wave + 4) * 512);
        if (wave < 2) gld16(g + (8 + wave) * 512 + lane * 8, l + (8 + wave) * 512);
    }
    __syncthreads();

    for (int t = 0; t < 16; t++) {
        // ---- prefetch tile t+1 first (other buffer; its prior readers
        //      drained at the last barrier) ----
        if (t < 15) {
            const unsigned short* g = sg + (size_t)(t + 1) * 5120;
            unsigned short* l = SB[(t + 1) & 1];
            gld16(g + wave * 512 + lane * 8, l + wave * 512);
            gld16(g + (wave + 4) * 512 + lane * 8, l + (wave + 4) * 512);
            if (wave < 2) gld16(g + (8 + wave) * 512 + lane * 8,
                                l + (8 + wave) * 512);
        }
        const unsigned short* Ks = SB[t & 1];
        const unsigned short* Vs = Ks + 2560;
        // ---- frag loads from LDS into regs ----
        bfrag kf[4]; f32x4 Ccf[4]; bfrag vfr[2][2];
        #pragma unroll
        for (int sub = 0; sub < 4; sub++) {
            kf[sub] = *(const bfrag*)&Ks[(sub * 16 + m15) * 40 + quad * 8];
            float c = *(const float*)&Ks[(sub * 16 + m15) * 40 + 32];
            Ccf[sub] = (f32x4){c, c, c, c};
        }
        #pragma unroll
        for (int kf2 = 0; kf2 < 2; kf2++)
            #pragma unroll
            for (int dt = 0; dt < 2; dt++)
                vfr[kf2][dt] = *(const bfrag*)&Vs[(dt * 16 + m15) * 72 +
                                                  kf2 * 32 + quad * 8];
        // ---- S = Q K^T + cf (8 MFMAs, cf in C-operand) ----
        f32x4 S[2][4];
        #pragma unroll
        for (int sub = 0; sub < 4; sub++) {
            S[0][sub] = __builtin_amdgcn_mfma_f32_16x16x32_bf16(Qa0, kf[sub], Ccf[sub], 0, 0, 0);
            S[1][sub] = __builtin_amdgcn_mfma_f32_16x16x32_bf16(Qa1, kf[sub], Ccf[sub], 0, 0, 0);
        }
        // ---- P = exp2(S); manual RTNE pair-pack into permuted cols ----
        #pragma unroll
        for (int tq = 0; tq < 2; tq++) {
            #pragma unroll
            for (int r = 0; r < 4; r++) {
                float p0 = exp2f(S[tq][0][r]);
                float p1 = exp2f(S[tq][1][r]);
                float p2 = exp2f(S[tq][2][r]);
                float p3 = exp2f(S[tq][3][r]);
                lrow[tq][r] += (p0 + p1) + (p2 + p3);
                uint2 dd;
                dd.x = (rtn16(p0) >> 16) | (rtn16(p1) & 0xffff0000u);
                dd.y = (rtn16(p2) >> 16) | (rtn16(p3) & 0xffff0000u);
                *(uint2*)&Pw[tq * 1152 + (quad * 4 + r) * 72 + 4 * m15] = dd;
            }
        }
        // ---- O += P V' (8 MFMAs) ----
        #pragma unroll
        for (int kf2 = 0; kf2 < 2; kf2++) {
            bfrag Pa0 = *(const bfrag*)&Pw[0 * 1152 + m15 * 72 + kf2 * 32 + quad * 8];
            bfrag Pa1 = *(const bfrag*)&Pw[1 * 1152 + m15 * 72 + kf2 * 32 + quad * 8];
            #pragma unroll
            for (int dt = 0; dt < 2; dt++) {
                O[0][dt] = __builtin_amdgcn_mfma_f32_16x16x32_bf16(Pa0, vfr[kf2][dt], O[0][dt], 0, 0, 0);
                O[1][dt] = __builtin_amdgcn_mfma_f32_16x16x32_bf16(Pa1, vfr[kf2][dt], O[1][dt], 0, 0, 0);
            }
        }
        __syncthreads();   // drains prefetch (vmcnt) + all waves done with bufs
    }
    // ---- reduce lrow over the 16 key-lanes ----
    #pragma unroll
    for (int tq = 0; tq < 2; tq++) {
        #pragma unroll
        for (int r = 0; r < 4; r++) {
            float s = lrow[tq][r];
            s += __shfl_xor(s, 1, 64);
            s += __shfl_xor(s, 2, 64);
            s += __shfl_xor(s, 4, 64);
            s += __shfl_xor(s, 8, 64);
            lrow[tq][r] = s;
        }
    }
    // ---- epilogue: O/l -> split hi/hi/lo bf16 into aout [16384][768] ----
    #pragma unroll
    for (int tq = 0; tq < 2; tq++) {
        #pragma unroll
        for (int r = 0; r < 4; r++) {
            float inv = 1.0f / lrow[tq][r];
            int row = b * NTOK + qbase + tq * 16 + quad * 4 + r;
            size_t rb = (size_t)row * 768;
            #pragma unroll
            for (int dt = 0; dt < 2; dt++) {
                float o = O[tq][dt][r] * inv;
                unsigned int hr = rtn16(o);
                unsigned short hu = hr >> 16;
                float hf = bits2f(hr & 0xffff0000u);
                unsigned short lu = rtn16(o - hf) >> 16;
                int col = h * 32 + dt * 16 + m15;
                aout[rb + col]       = hu;
                aout[rb + 256 + col] = hu;
                aout[rb + 512 + col] = lu;
            }
        }
    }
}

// ---------------------------------------------------------------------------
extern "C" void kernel_launch(void* const* d_in, const int* in_sizes, int n_in,
                              void* d_out, int out_size, void* d_ws, size_t ws_size,
                              hipStream_t stream) {
    const float* x        = (const float*)d_in[0];
    const float* x_source = (const float*)d_in[1];
    const float* loc      = (const float*)d_in[2];
    const float* conf     = (const float*)d_in[3];
    const float* Wq       = (const float*)d_in[4];
    const float* Wk       = (const float*)d_in[5];
    const float* Wv       = (const float*)d_in[6];
    const float* srw      = (const float*)d_in[7];
    const float* srb      = (const float*)d_in[8];
    const float* lnw      = (const float*)d_in[9];
    const float* lnb      = (const float*)d_in[10];
    const float* Wp       = (const float*)d_in[11];
    const float* bp       = (const float*)d_in[12];
    float* out = (float*)d_out;
    float* ws  = (float*)d_ws;

    // ---- workspace arena (float offsets) ----
    // A0 [0, 8388608): feat during scatter/recon; overlaid afterwards:
    float* feat = ws;
    unsigned short* Qbf = (unsigned short*)ws;                  // 4,194,304 u16
    unsigned short* stg = (unsigned short*)(ws + 2097152);      // 1,310,720 u16
    unsigned short* wqb = (unsigned short*)(ws + 2752512);      //    65,536 u16
    unsigned short* wkb = (unsigned short*)(ws + 2785280);      //  (B of KV:
    unsigned short* wvb = (unsigned short*)(ws + 2818048);      //   adjacent)
    unsigned short* wpb = (unsigned short*)(ws + 2850816);      //   196,608 u16
    float*          xsb  = ws + 2949120;                        //   524,288 f
    unsigned short* xsbf = (unsigned short*)(ws + 3473408);     //   524,288 u16
    // A1 maskr
    float* maskr = ws + 8388608;                                //    32,768 f
    // A2 [8421376, ...): apatch -> aouts overlay; wTb after (dead early)
    unsigned short* apatch = (unsigned short*)(ws + 8421376);   // 8,388,608 u16
    unsigned short* aouts  = (unsigned short*)(ws + 8421376);   // 12,582,912 u16
    unsigned short* wTb    = (unsigned short*)(ws + 12615680);  // 1,048,576 u16

    const float SC = 0.17677669529663687f * 1.4426950408889634f; // scale*log2e

    hipMemsetAsync(feat, 0, (size_t)(8388608 + 32768) * sizeof(float), stream);

    scatter_k  <<<16384, 256, 0, stream>>>(x_source, loc, feat, maskr);
    recon_fused<<<32768, 256, 0, stream>>>(feat, maskr, apatch);
    prep_misc  <<<6600, 256, 0, stream>>>(srw, Wq, Wk, Wv, Wp, conf, srb,
                                          wTb, wqb, wkb, wvb, wpb, stg, xsb);
    // conv as GEMM (2048 x 256 x 4096), split-K 8, atomic into bias-inited xsb
    bgemm<<<dim3(2, 16, 8), 256, 0, stream>>>(apatch, nullptr, wTb, nullptr,
                                              xsb, nullptr,
                                              2048, 256, 4096, 8, 1, 1.f);
    ln_k<<<2048, 256, 0, stream>>>(xsb, lnw, lnb, xsbf);
    // K and V fused (B = [Wk;Wv], N=512) -> STG tiles (K rows + permuted V')
    bgemm<<<dim3(4, 16, 1), 256, 0, stream>>>(xsbf, nullptr, wkb, nullptr,
                                              nullptr, stg,
                                              2048, 512, 256, 1, 3, 1.f);
    // Q = x@Wq^T * scale*log2e (A read fp32 directly) -> [bh][8192][32] bf16
    bgemm<<<dim3(2, 128, 1), 256, 0, stream>>>(nullptr, x, wqb, nullptr,
                                               nullptr, Qbf,
                                               16384, 256, 256, 1, 2, SC);
    attn_v6<<<dim3(64, 16), 256, 0, stream>>>(Qbf, stg, aouts);
    // final projection, fp32-accurate K-expansion split (K=768)
    bgemm<<<dim3(2, 128, 1), 256, 0, stream>>>(aouts, nullptr, wpb, bp,
                                               out, nullptr,
                                               16384, 256, 768, 1, 0, 1.f);
}

// Round 8
// 277.321 us; speedup vs baseline: 1.3936x; 1.0726x over previous
//
#include <hip/hip_runtime.h>
#include <hip/hip_bf16.h>
#include <cstddef>
#include <cstdint>

#define NTOK 8192      // N
#define CD   256       // C
#define HWPIX 16384    // H*W = 128*128
#define WIDTH 128
#define NSEQ 1024      // Ns

typedef __attribute__((ext_vector_type(8))) short bfrag;   // 8 bf16 = 4 VGPRs
typedef __attribute__((ext_vector_type(4))) float f32x4;

__device__ inline unsigned short f2bfu(float f) {
    __hip_bfloat16 h = __float2bfloat16(f);   // RTNE
    unsigned short u;
    __builtin_memcpy(&u, &h, 2);
    return u;
}
__device__ inline unsigned int rtn16(float f) {
    unsigned int u = __builtin_bit_cast(unsigned int, f);
    return u + 0x7fffu + ((u >> 16) & 1u);
}
__device__ inline float bits2f(unsigned int u) {
    return __builtin_bit_cast(float, u);
}
__device__ inline bfrag cvt8(float4 a, float4 b) {
    bfrag r;
    r[0] = (short)f2bfu(a.x); r[1] = (short)f2bfu(a.y);
    r[2] = (short)f2bfu(a.z); r[3] = (short)f2bfu(a.w);
    r[4] = (short)f2bfu(b.x); r[5] = (short)f2bfu(b.y);
    r[6] = (short)f2bfu(b.z); r[7] = (short)f2bfu(b.w);
    return r;
}
// async global -> LDS, 16 B per lane; lds base wave-uniform, HW adds lane*16
__device__ inline void gld16(const unsigned short* g, const unsigned short* l) {
    __builtin_amdgcn_global_load_lds(
        (const __attribute__((address_space(1))) unsigned int*)g,
        (__attribute__((address_space(3))) unsigned int*)l, 16, 0, 0);
}

// ---------------------------------------------------------------------------
// 1. fused token2map scatter + all small prep work.
//    ALL prep outputs live OUTSIDE the live feat region [0, 8.4M floats)
//    (R7 bug: prep wrote into feat-overlapping buffers while scatter ran).
//    [0,16384)        scatter: segment-sum x_source -> feat, count -> maskr
//    [16384,20480)    wtrans srw -> wTb
//    [20480,20672)    cvt Wq/Wk/Wv -> wqb/wkb/wvb (wkb,wvb adjacent)
//    [20672,20928)    Wp split [bh|bl|bh] -> wpb
//    [20928,20936)    cf = conf*log2e into STG K-row pads (all 8 heads)
//    [20936,22984)    xsb init with srb (conv split-K accumulator)
// ---------------------------------------------------------------------------
__global__ __launch_bounds__(256) void scatter_prep(
        const float* __restrict__ xsrc, const float* __restrict__ loc,
        float* __restrict__ feat, float* __restrict__ maskr,
        const float* __restrict__ srw, const float* __restrict__ Wq,
        const float* __restrict__ Wk, const float* __restrict__ Wv,
        const float* __restrict__ Wp, const float* __restrict__ conf,
        const float* __restrict__ srb,
        unsigned short* __restrict__ wTb, unsigned short* __restrict__ wqb,
        unsigned short* __restrict__ wkb, unsigned short* __restrict__ wvb,
        unsigned short* __restrict__ wpb, unsigned short* __restrict__ stg,
        float* __restrict__ xsb) {
    int gid = blockIdx.x, tid = threadIdx.x;
    if (gid < 16384) {                      // scatter
        int token = gid;
        int b = token >> 13;
        float lx = loc[token * 2 + 0];
        float ly = loc[token * 2 + 1];
        lx = fminf(fmaxf(lx, 0.f), 1.f) * 127.0f;
        ly = fminf(fmaxf(ly, 0.f), 1.f) * 127.0f;
        int ix = __float2int_rn(lx);
        int iy = __float2int_rn(ly);
        int p = b * HWPIX + iy * WIDTH + ix;
        atomicAdd(&feat[(size_t)p * CD + tid], xsrc[(size_t)token * CD + tid]);
        if (tid == 0) atomicAdd(&maskr[p], 1.0f);
    } else if (gid < 20480) {               // sr_w transpose
        int idx = (gid - 16384) * 256 + tid;
        int co = idx >> 12;
        int rest = idx & 4095;
        int k16 = rest >> 8;
        int ci = rest & 255;
        int kh = k16 >> 2, kw = k16 & 3;
        wTb[idx] = f2bfu(srw[(size_t)co * 4096 + ci * 16 + kh * 4 + kw]);
    } else if (gid < 20672) {               // weight fp32 -> bf16
        const float* s; unsigned short* d; int base;
        if (gid < 20544)      { s = Wq; d = wqb; base = gid - 20480; }
        else if (gid < 20608) { s = Wk; d = wkb; base = gid - 20544; }
        else                  { s = Wv; d = wvb; base = gid - 20608; }
        int i = (base * 256 + tid) * 4;
        float4 v = *(const float4*)(s + i);
        ushort4 o;
        o.x = f2bfu(v.x); o.y = f2bfu(v.y); o.z = f2bfu(v.z); o.w = f2bfu(v.w);
        *(ushort4*)(d + i) = o;
    } else if (gid < 20928) {               // Wp split [bh|bl|bh]
        int n = gid - 20672, t = tid;
        float w = Wp[n * 256 + t];
        unsigned short hu = f2bfu(w);
        float hf = bits2f(((unsigned int)hu) << 16);
        unsigned short lu = f2bfu(w - hf);
        wpb[n * 768 + t]       = hu;
        wpb[n * 768 + 256 + t] = lu;
        wpb[n * 768 + 512 + t] = hu;
    } else if (gid < 20936) {               // cf pads into STG
        int idx = (gid - 20928) * 256 + tid;  // b*1024 + key
        int b = idx >> 10, key = idx & 1023;
        int tile = key >> 6, rin = key & 63;
        float val = conf[idx] * 1.4426950408889634f;
        #pragma unroll
        for (int h = 0; h < 8; h++)
            *(float*)&stg[((size_t)((b * 8 + h) * 16 + tile)) * 5120
                          + rin * 40 + 32] = val;
    } else {                                // xsb init with bias
        int row = gid - 20936;
        xsb[(size_t)row * 256 + tid] = srb[tid];
    }
}

// ---------------------------------------------------------------------------
// 2. fused normalize + 3x3 gaussian reconstruct + 4x4 patch gather -> bf16 A
// ---------------------------------------------------------------------------
__global__ __launch_bounds__(256) void recon_fused(const float* __restrict__ feat,
        const float* __restrict__ maskr, unsigned short* __restrict__ apatch) {
    __shared__ float sw[9];
    __shared__ float sgb[9];
    __shared__ int   snp[9];
    __shared__ float sci;
    __shared__ float sbc;
    int p = blockIdx.x;
    int b = p >> 14;
    int pix = p & 16383;
    int y = pix >> 7, x = pix & 127;
    int c = threadIdx.x;
    const float e1 = 0.882496902584595f;
    const float e2 = 0.778800783071405f;
    const float snorm = 1.0f / (1.0f + 4.0f * e1 + 4.0f * e2);
    if (c < 9) {
        int dy = c / 3 - 1, dx = c % 3 - 1;
        int yy = y + dy, xx = x + dx;
        bool valid = (yy >= 0 && yy <= 127 && xx >= 0 && xx <= 127);
        int np_ = valid ? (b * HWPIX + yy * WIDTH + xx) : p;
        int manh = (dy != 0) + (dx != 0);
        float g = ((manh == 2) ? e2 : (manh == 1) ? e1 : 1.0f) * snorm;
        float m = maskr[np_];
        float bin = (m > 0.f) ? 1.f : 0.f;
        float inv = 1.0f / (m + 1e-6f);
        float vb = valid ? bin : 0.f;
        sw[c]  = g * vb * inv;
        sgb[c] = g * vb;
        snp[c] = np_;
        if (c == 4) { sci = bin * inv; sbc = bin; }
    }
    __syncthreads();
    float gm = ((sgb[0] + sgb[1]) + (sgb[2] + sgb[3])) +
               ((sgb[4] + sgb[5]) + (sgb[6] + sgb[7])) + sgb[8];
    float gf = 0.f;
    #pragma unroll
    for (int j = 0; j < 9; j++)
        gf += sw[j] * feat[(size_t)snp[j] * CD + c];
    float f_int = (gm > 0.f) ? (gf / (gm + 1e-6f)) : 0.f;
    float fc = feat[(size_t)p * CD + c] * sci;
    float res = fc + (1.f - sbc) * f_int;
    int r = b * 1024 + (y >> 2) * 32 + (x >> 2);
    int k16 = (y & 3) * 4 + (x & 3);
    apatch[(size_t)r * 4096 + k16 * 256 + c] = f2bfu(res);
}

// ---------------------------------------------------------------------------
// 3. bf16 MFMA GEMM body: 128x128 tile, 4 waves, BK=32. A bf16 (fp32 if Af).
//    mode 0: C fp32 = acc + bias[col]
//    mode 1: atomicAdd into C (split-K; C pre-initialized with bias)
//    mode 2: bf16 permuted write (Q): dstb[((b*8+h)<<13 | r)*32 + d] = acc*mult
//    mode 3: KV fused -> STG tiles. col<256: K bf16 at [tile]*5120+rin*40+d.
//            col>=256: V' bf16 permuted at [tile]*5120+2560+d*72+(4*m+sub).
// ---------------------------------------------------------------------------
__device__ __forceinline__ void bgemm_body(
        unsigned short* As, unsigned short* Bs,
        const unsigned short* __restrict__ A, const float* __restrict__ Af,
        const unsigned short* __restrict__ B, const float* __restrict__ bias,
        float* __restrict__ C, unsigned short* __restrict__ dstb,
        int M, int N, int K, int kSplit, int mode, float mult,
        int bx, int by, int bz) {
    int tid = threadIdx.x;
    int wave = tid >> 6, lane = tid & 63, m15 = lane & 15, quad = lane >> 4;
    int wr = (wave >> 1) * 64, wc = (wave & 1) * 64;
    int m0 = by * 128, n0 = bx * 128;
    int kchunk = K / kSplit, k0 = bz * kchunk;
    int srow = tid >> 2, sko = (tid & 3) * 8;
    f32x4 acc[4][4];
    #pragma unroll
    for (int i = 0; i < 4; i++)
        #pragma unroll
        for (int j = 0; j < 4; j++) acc[i][j] = (f32x4){0.f, 0.f, 0.f, 0.f};
    const unsigned short* Ag = A + (size_t)(m0 + srow) * K + k0 + sko;
    const float* Afg = Af + (size_t)(m0 + srow) * K + k0 + sko;
    const unsigned short* Bg = B + (size_t)(n0 + srow) * K + k0 + sko;
    for (int kk = 0; kk < kchunk; kk += 32) {
        bfrag a0, a1;
        if (Af) {
            float4 f0 = *(const float4*)(Afg + kk);
            float4 f1 = *(const float4*)(Afg + kk + 4);
            float4 f2 = *(const float4*)(Afg + (size_t)64 * K + kk);
            float4 f3 = *(const float4*)(Afg + (size_t)64 * K + kk + 4);
            a0 = cvt8(f0, f1);
            a1 = cvt8(f2, f3);
        } else {
            a0 = *(const bfrag*)(Ag + kk);
            a1 = *(const bfrag*)(Ag + (size_t)64 * K + kk);
        }
        bfrag b0 = *(const bfrag*)(Bg + kk);
        bfrag b1 = *(const bfrag*)(Bg + (size_t)64 * K + kk);
        __syncthreads();
        *(bfrag*)&As[srow * 32 + sko] = a0;
        *(bfrag*)&As[(srow + 64) * 32 + sko] = a1;
        *(bfrag*)&Bs[srow * 32 + sko] = b0;
        *(bfrag*)&Bs[(srow + 64) * 32 + sko] = b1;
        __syncthreads();
        bfrag af[4], bfr[4];
        #pragma unroll
        for (int mi = 0; mi < 4; mi++)
            af[mi] = *(const bfrag*)&As[(wr + mi * 16 + m15) * 32 + quad * 8];
        #pragma unroll
        for (int ni = 0; ni < 4; ni++)
            bfr[ni] = *(const bfrag*)&Bs[(wc + ni * 16 + m15) * 32 + quad * 8];
        #pragma unroll
        for (int mi = 0; mi < 4; mi++)
            #pragma unroll
            for (int ni = 0; ni < 4; ni++)
                acc[mi][ni] = __builtin_amdgcn_mfma_f32_16x16x32_bf16(
                                  af[mi], bfr[ni], acc[mi][ni], 0, 0, 0);
    }
    if (mode == 2) {
        #pragma unroll
        for (int mi = 0; mi < 4; mi++) {
            #pragma unroll
            for (int i = 0; i < 4; i++) {
                int row = m0 + wr + mi * 16 + quad * 4 + i;
                int b = row >> 13, r = row & 8191;
                #pragma unroll
                for (int ni = 0; ni < 4; ni++) {
                    int col = n0 + wc + ni * 16 + m15;
                    int h = col >> 5, d = col & 31;
                    size_t di = ((((size_t)(b * 8 + h)) << 13) + r) * 32 + d;
                    dstb[di] = f2bfu(acc[mi][ni][i] * mult);
                }
            }
        }
    } else if (mode == 3) {
        #pragma unroll
        for (int mi = 0; mi < 4; mi++) {
            #pragma unroll
            for (int i = 0; i < 4; i++) {
                int row = m0 + wr + mi * 16 + quad * 4 + i;
                int b = row >> 10, key = row & 1023;
                int tile = key >> 6, rin = key & 63;
                #pragma unroll
                for (int ni = 0; ni < 4; ni++) {
                    int col = n0 + wc + ni * 16 + m15;
                    unsigned short v = f2bfu(acc[mi][ni][i]);
                    if (col < 256) {        // K part
                        int h = col >> 5, d = col & 31;
                        size_t di = ((size_t)((b * 8 + h) * 16 + tile)) * 5120
                                    + rin * 40 + d;
                        dstb[di] = v;
                    } else {                // V' part (permuted transpose)
                        int c2 = col - 256;
                        int h = c2 >> 5, d = c2 & 31;
                        int m = rin & 15, sub = rin >> 4;
                        size_t di = ((size_t)((b * 8 + h) * 16 + tile)) * 5120
                                    + 2560 + d * 72 + 4 * m + sub;
                        dstb[di] = v;
                    }
                }
            }
        }
    } else {
        #pragma unroll
        for (int mi = 0; mi < 4; mi++) {
            #pragma unroll
            for (int i = 0; i < 4; i++) {
                size_t row = (size_t)(m0 + wr + mi * 16 + quad * 4 + i) * N;
                #pragma unroll
                for (int ni = 0; ni < 4; ni++) {
                    int col = n0 + wc + ni * 16 + m15;
                    float v = acc[mi][ni][i];
                    if (mode == 1) atomicAdd(&C[row + col], v);
                    else C[row + col] = v + (bias ? bias[col] : 0.f);
                }
            }
        }
    }
}

__global__ __launch_bounds__(256) void bgemm(const unsigned short* A,
        const float* Af, const unsigned short* B, const float* bias,
        float* C, unsigned short* dstb,
        int M, int N, int K, int kSplit, int mode, float mult) {
    __shared__ __align__(16) unsigned short As[128 * 32];
    __shared__ __align__(16) unsigned short Bs[128 * 32];
    bgemm_body(As, Bs, A, Af, B, bias, C, dstb, M, N, K, kSplit, mode, mult,
               blockIdx.x, blockIdx.y, blockIdx.z);
}

// Q-GEMM (256 blocks) and KV-GEMM (64 blocks) co-scheduled in one launch
__global__ __launch_bounds__(256) void qkv_fused(const float* x,
        const unsigned short* wqb, const unsigned short* xsbf,
        const unsigned short* wkb, unsigned short* Qbf,
        unsigned short* stg, float SC) {
    __shared__ __align__(16) unsigned short As[128 * 32];
    __shared__ __align__(16) unsigned short Bs[128 * 32];
    int g = blockIdx.x;
    if (g < 256) {
        // Q = x@Wq^T * scale*log2e (A fp32) -> [bh][8192][32] bf16
        bgemm_body(As, Bs, nullptr, x, wqb, nullptr, nullptr, Qbf,
                   16384, 256, 256, 1, 2, SC, g & 1, g >> 1, 0);
    } else {
        // K|V fused (B=[Wk;Wv], N=512) -> STG tiles (K rows + permuted V')
        int g2 = g - 256;
        bgemm_body(As, Bs, xsbf, nullptr, wkb, nullptr, nullptr, stg,
                   2048, 512, 256, 1, 3, 1.f, g2 & 3, g2 >> 2, 0);
    }
}

// ---------------------------------------------------------------------------
// 4. LayerNorm (C=256), fp32 in -> bf16 out
// ---------------------------------------------------------------------------
__global__ __launch_bounds__(256) void ln_k(const float* __restrict__ xs,
        const float* __restrict__ w, const float* __restrict__ bvec,
        unsigned short* __restrict__ outb) {
    int row = blockIdx.x;
    int c = threadIdx.x;
    float v = xs[(size_t)row * 256 + c];
    __shared__ float red[4];
    float s = v;
    #pragma unroll
    for (int o = 32; o >= 1; o >>= 1) s += __shfl_down(s, o, 64);
    if ((c & 63) == 0) red[c >> 6] = s;
    __syncthreads();
    float mean = (red[0] + red[1] + red[2] + red[3]) * (1.f / 256.f);
    __syncthreads();
    float d = v - mean;
    float s2 = d * d;
    #pragma unroll
    for (int o = 32; o >= 1; o >>= 1) s2 += __shfl_down(s2, o, 64);
    if ((c & 63) == 0) red[c >> 6] = s2;
    __syncthreads();
    float var = (red[0] + red[1] + red[2] + red[3]) * (1.f / 256.f);
    float r = 1.0f / sqrtf(var + 1e-5f);
    outb[(size_t)row * 256 + c] = f2bfu(d * r * w[c] + bvec[c]);
}

// ---------------------------------------------------------------------------
// 5. MFMA flash attention v7: 32 q-rows/wave, async LDS staging (dbuf),
//    v5 ordering (frag ds_reads BEFORE prefetch issue), cf folded into the
//    QK MFMA C-operand, cvt_pk bf16 pack. One barrier per tile.
// ---------------------------------------------------------------------------
__global__ __launch_bounds__(256, 4) void attn_v7(
        const unsigned short* __restrict__ Qb,   // [bh][8192][32] *scale*log2e
        const unsigned short* __restrict__ STG,  // [bh][16][5120 u16]
        unsigned short* __restrict__ aout) {     // [16384][768] hi|hi|lo
    __shared__ __align__(16) unsigned short SB[2][5120];
    __shared__ __align__(16) unsigned short Pl[4][2304];
    int tid  = threadIdx.x;
    int wave = tid >> 6;
    int lane = tid & 63;
    int m15  = lane & 15;
    int quad = lane >> 4;
    int bh = blockIdx.y;
    int b  = bh >> 3;
    int h  = bh & 7;
    int qbase = blockIdx.x * 128 + wave * 32;

    const unsigned short* qp = Qb + ((size_t)bh * NTOK + qbase) * 32;
    bfrag Qa0 = *(const bfrag*)(qp + m15 * 32 + quad * 8);
    bfrag Qa1 = *(const bfrag*)(qp + (16 + m15) * 32 + quad * 8);
    const unsigned short* sg = STG + (size_t)bh * 16 * 5120;
    unsigned short* Pw = Pl[wave];

    f32x4 O[2][2];
    float lrow[2][4];
    #pragma unroll
    for (int t = 0; t < 2; t++) {
        #pragma unroll
        for (int dt = 0; dt < 2; dt++) O[t][dt] = (f32x4){0.f, 0.f, 0.f, 0.f};
        #pragma unroll
        for (int r = 0; r < 4; r++) lrow[t][r] = 0.f;
    }

    // stage tile 0: 10240 B = 10 chunks of 1 KB; wave w: chunks w, w+4;
    // waves 0,1 also take chunks 8,9 (wave-uniform branches)
    {
        const unsigned short* g = sg;
        unsigned short* l = SB[0];
        gld16(g + wave * 512 + lane * 8, l + wave * 512);
        gld16(g + (wave + 4) * 512 + lane * 8, l + (wave + 4) * 512);
        if (wave < 2) gld16(g + (8 + wave) * 512 + lane * 8, l + (8 + wave) * 512);
    }
    __syncthreads();

    for (int t = 0; t < 16; t++) {
        const unsigned short* Ks = SB[t & 1];
        const unsigned short* Vs = Ks + 2560;
        // ---- frag loads from LDS into regs (before DMA burst) ----
        bfrag kf[4]; f32x4 Ccf[4]; bfrag vfr[2][2];
        #pragma unroll
        for (int sub = 0; sub < 4; sub++) {
            kf[sub] = *(const bfrag*)&Ks[(sub * 16 + m15) * 40 + quad * 8];
            float c = *(const float*)&Ks[(sub * 16 + m15) * 40 + 32];
            Ccf[sub] = (f32x4){c, c, c, c};
        }
        #pragma unroll
        for (int kf2 = 0; kf2 < 2; kf2++)
            #pragma unroll
            for (int dt = 0; dt < 2; dt++)
                vfr[kf2][dt] = *(const bfrag*)&Vs[(dt * 16 + m15) * 72 +
                                                  kf2 * 32 + quad * 8];
        // ---- now issue async prefetch of tile t+1 (overlaps compute) ----
        if (t < 15) {
            const unsigned short* g = sg + (size_t)(t + 1) * 5120;
            unsigned short* l = SB[(t + 1) & 1];
            gld16(g + wave * 512 + lane * 8, l + wave * 512);
            gld16(g + (wave + 4) * 512 + lane * 8, l + (wave + 4) * 512);
            if (wave < 2) gld16(g + (8 + wave) * 512 + lane * 8,
                                l + (8 + wave) * 512);
        }
        // ---- S = Q K^T + cf (8 MFMAs, cf in C-operand) ----
        f32x4 S[2][4];
        #pragma unroll
        for (int sub = 0; sub < 4; sub++) {
            S[0][sub] = __builtin_amdgcn_mfma_f32_16x16x32_bf16(Qa0, kf[sub], Ccf[sub], 0, 0, 0);
            S[1][sub] = __builtin_amdgcn_mfma_f32_16x16x32_bf16(Qa1, kf[sub], Ccf[sub], 0, 0, 0);
        }
        // ---- P = exp2(S); cvt_pk pack into permuted cols ----
        #pragma unroll
        for (int tq = 0; tq < 2; tq++) {
            #pragma unroll
            for (int r = 0; r < 4; r++) {
                float2 p01, p23;
                p01.x = exp2f(S[tq][0][r]);
                p01.y = exp2f(S[tq][1][r]);
                p23.x = exp2f(S[tq][2][r]);
                p23.y = exp2f(S[tq][3][r]);
                lrow[tq][r] += (p01.x + p01.y) + (p23.x + p23.y);
                __hip_bfloat162 q01 = __float22bfloat162_rn(p01);
                __hip_bfloat162 q23 = __float22bfloat162_rn(p23);
                uint2 dd;
                __builtin_memcpy(&dd.x, &q01, 4);
                __builtin_memcpy(&dd.y, &q23, 4);
                *(uint2*)&Pw[tq * 1152 + (quad * 4 + r) * 72 + 4 * m15] = dd;
            }
        }
        // ---- O += P V' (8 MFMAs) ----
        #pragma unroll
        for (int kf2 = 0; kf2 < 2; kf2++) {
            bfrag Pa0 = *(const bfrag*)&Pw[0 * 1152 + m15 * 72 + kf2 * 32 + quad * 8];
            bfrag Pa1 = *(const bfrag*)&Pw[1 * 1152 + m15 * 72 + kf2 * 32 + quad * 8];
            #pragma unroll
            for (int dt = 0; dt < 2; dt++) {
                O[0][dt] = __builtin_amdgcn_mfma_f32_16x16x32_bf16(Pa0, vfr[kf2][dt], O[0][dt], 0, 0, 0);
                O[1][dt] = __builtin_amdgcn_mfma_f32_16x16x32_bf16(Pa1, vfr[kf2][dt], O[1][dt], 0, 0, 0);
            }
        }
        __syncthreads();   // drains prefetch (vmcnt) + all waves done with bufs
    }
    // ---- reduce lrow over the 16 key-lanes ----
    #pragma unroll
    for (int tq = 0; tq < 2; tq++) {
        #pragma unroll
        for (int r = 0; r < 4; r++) {
            float s = lrow[tq][r];
            s += __shfl_xor(s, 1, 64);
            s += __shfl_xor(s, 2, 64);
            s += __shfl_xor(s, 4, 64);
            s += __shfl_xor(s, 8, 64);
            lrow[tq][r] = s;
        }
    }
    // ---- epilogue: O/l -> split hi/hi/lo bf16 into aout [16384][768] ----
    #pragma unroll
    for (int tq = 0; tq < 2; tq++) {
        #pragma unroll
        for (int r = 0; r < 4; r++) {
            float inv = 1.0f / lrow[tq][r];
            int row = b * NTOK + qbase + tq * 16 + quad * 4 + r;
            size_t rb = (size_t)row * 768;
            #pragma unroll
            for (int dt = 0; dt < 2; dt++) {
                float o = O[tq][dt][r] * inv;
                unsigned int hr = rtn16(o);
                unsigned short hu = hr >> 16;
                float hf = bits2f(hr & 0xffff0000u);
                unsigned short lu = rtn16(o - hf) >> 16;
                int col = h * 32 + dt * 16 + m15;
                aout[rb + col]       = hu;
                aout[rb + 256 + col] = hu;
                aout[rb + 512 + col] = lu;
            }
        }
    }
}

// ---------------------------------------------------------------------------
extern "C" void kernel_launch(void* const* d_in, const int* in_sizes, int n_in,
                              void* d_out, int out_size, void* d_ws, size_t ws_size,
                              hipStream_t stream) {
    const float* x        = (const float*)d_in[0];
    const float* x_source = (const float*)d_in[1];
    const float* loc      = (const float*)d_in[2];
    const float* conf     = (const float*)d_in[3];
    const float* Wq       = (const float*)d_in[4];
    const float* Wk       = (const float*)d_in[5];
    const float* Wv       = (const float*)d_in[6];
    const float* srw      = (const float*)d_in[7];
    const float* srb      = (const float*)d_in[8];
    const float* lnw      = (const float*)d_in[9];
    const float* lnb      = (const float*)d_in[10];
    const float* Wp       = (const float*)d_in[11];
    const float* bp       = (const float*)d_in[12];
    float* out = (float*)d_out;
    float* ws  = (float*)d_ws;

    // ---- workspace arena (float offsets); ~65.4 MB total ----
    // A0 [0, 8388608): feat during scatter/recon; Qbf overlaid after recon.
    float* feat = ws;
    unsigned short* Qbf = (unsigned short*)ws;                  // 4,194,304 u16
    // A1 maskr
    float* maskr = ws + 8388608;                                //    32,768 f
    // A2 [8421376, 14712832): apatch (recon out) -> aouts (attn out) overlay;
    //    wTb at the tail (dead after conv GEMM, before aouts written).
    unsigned short* apatch = (unsigned short*)(ws + 8421376);   // 8,388,608 u16
    unsigned short* aouts  = (unsigned short*)(ws + 8421376);   // 12,582,912 u16
    unsigned short* wTb    = (unsigned short*)(ws + 12615680);  // 1,048,576 u16
    // A3 [14712832, 16351232): scatter_prep outputs — NEVER overlaps feat.
    unsigned short* stg  = (unsigned short*)(ws + 14712832);    // 1,310,720 u16
    unsigned short* wqb  = (unsigned short*)(ws + 15368192);    //    65,536 u16
    unsigned short* wkb  = (unsigned short*)(ws + 15400960);    //  (B of KV:
    unsigned short* wvb  = (unsigned short*)(ws + 15433728);    //   adjacent)
    unsigned short* wpb  = (unsigned short*)(ws + 15466496);    //   196,608 u16
    float*          xsb  = ws + 15564800;                       //   524,288 f
    unsigned short* xsbf = (unsigned short*)(ws + 16089088);    //   524,288 u16

    const float SC = 0.17677669529663687f * 1.4426950408889634f; // scale*log2e

    // zero scatter accumulators (feat + maskr adjacent)
    hipMemsetAsync(feat, 0, (size_t)(8388608 + 32768) * sizeof(float), stream);

    scatter_prep<<<22984, 256, 0, stream>>>(x_source, loc, feat, maskr,
                                            srw, Wq, Wk, Wv, Wp, conf, srb,
                                            wTb, wqb, wkb, wvb, wpb, stg, xsb);
    recon_fused<<<32768, 256, 0, stream>>>(feat, maskr, apatch);
    // conv as GEMM (2048 x 256 x 4096), split-K 8, atomic into bias-inited xsb
    bgemm<<<dim3(2, 16, 8), 256, 0, stream>>>(apatch, nullptr, wTb, nullptr,
                                              xsb, nullptr,
                                              2048, 256, 4096, 8, 1, 1.f);
    ln_k<<<2048, 256, 0, stream>>>(xsb, lnw, lnb, xsbf);
    // Q-GEMM (256 blocks) + KV-GEMM (64 blocks) in one launch
    qkv_fused<<<320, 256, 0, stream>>>(x, wqb, xsbf, wkb, Qbf, stg, SC);
    attn_v7<<<dim3(64, 16), 256, 0, stream>>>(Qbf, stg, aouts);
    // final projection, fp32-accurate K-expansion split (K=768)
    bgemm<<<dim3(2, 128, 1), 256, 0, stream>>>(aouts, nullptr, wpb, bp,
                                               out, nullptr,
                                               16384, 256, 768, 1, 0, 1.f);
}